// Round 1
// baseline (1716.066 us; speedup 1.0000x reference)
//
#include <hip/hip_runtime.h>
#include <stdint.h>
#include <math.h>

// RPN proposal filtering: decode -> clip -> validity mask -> stable top-2000
// -> greedy NMS (IoU > 0.7) -> first 1000 kept -> (B, 1000, 5).
//
// Workspace layout (~31 MB): keys (B*A u32), hist (B*65536 u32), thresh,
// cnts, cand_sort (B*4096 u64), cand_box (B*4096 f4), sel_box (B*2048 f4),
// sel_score (B*2048 f32), mask (B*2048*32 u64).

#define IMGF 1024.0f
#define PRE_NMS 2000
#define POST_NMS 1000
#define NMS_THR 0.7f
#define MIN_SZ 16.0f
#define CAP 4096          // candidate buffer per batch (power of 2 for bitonic)
#define SEL 2048          // padded selection stride (>= PRE_NMS)
#define NW (SEL / 64)     // 32 mask words per row
#define NBUCK 65536

// Order-preserving float -> u32 key (all floats incl. -inf totally ordered).
__device__ __forceinline__ uint32_t f2key(float f) {
  uint32_t u = __float_as_uint(f);
  return (u & 0x80000000u) ? ~u : (u | 0x80000000u);
}
__device__ __forceinline__ float key2f(uint32_t k) {
  uint32_t u = (k & 0x80000000u) ? (k & 0x7FFFFFFFu) : ~k;
  return __uint_as_float(u);
}

// Mirrors reference _decode + clip, fp32.
__device__ __forceinline__ float4 decode_clip(float4 anc, float4 dlt) {
  float aw = anc.z - anc.x;
  float ah = anc.w - anc.y;
  float ax = anc.x + 0.5f * aw;
  float ay = anc.y + 0.5f * ah;
  float dw = fminf(dlt.z, 4.0f);
  float dh = fminf(dlt.w, 4.0f);
  float px = dlt.x * aw + ax;
  float py = dlt.y * ah + ay;
  float pw = expf(dw) * aw;
  float ph = expf(dh) * ah;
  float x1 = px - 0.5f * pw, y1 = py - 0.5f * ph;
  float x2 = px + 0.5f * pw, y2 = py + 0.5f * ph;
  x1 = fminf(fmaxf(x1, 0.0f), IMGF);
  y1 = fminf(fmaxf(y1, 0.0f), IMGF);
  x2 = fminf(fmaxf(x2, 0.0f), IMGF);
  y2 = fminf(fmaxf(y2, 0.0f), IMGF);
  return make_float4(x1, y1, x2, y2);
}

// K1: per-(b,a) masked-score sortable key.
__global__ void k_decode_keys(const float4* __restrict__ anchors,
                              const float4* __restrict__ deltas,
                              const float* __restrict__ scores,
                              uint32_t* __restrict__ keys,
                              int A, int BA) {
  int i = blockIdx.x * blockDim.x + threadIdx.x;
  if (i >= BA) return;
  int a = i % A;
  float4 box = decode_clip(anchors[a], deltas[i]);
  bool valid = (box.z - box.x >= MIN_SZ) && (box.w - box.y >= MIN_SZ);
  float ms = valid ? scores[i] : -INFINITY;
  keys[i] = f2key(ms);
}

// K2: 65536-bucket histogram of key high 16 bits, per batch.
__global__ void k_hist(const uint32_t* __restrict__ keys,
                       uint32_t* __restrict__ hist, int A, int BA) {
  int i = blockIdx.x * blockDim.x + threadIdx.x;
  if (i >= BA) return;
  int b = i / A;
  atomicAdd(&hist[(size_t)b * NBUCK + (keys[i] >> 16)], 1u);
}

// K3: find bucket beta s.t. count(key>>16 >= beta) >= PRE_NMS > count(>= beta+1).
__global__ void k_findthresh(const uint32_t* __restrict__ hist,
                             uint32_t* __restrict__ thresh,
                             uint32_t* __restrict__ cnts) {
  int b = blockIdx.x;
  int t = threadIdx.x;  // 256 threads
  __shared__ uint32_t csum[256];
  __shared__ uint32_t cbuck[256];
  __shared__ int s_tc;
  __shared__ uint32_t s_cum;
  const uint32_t* h = hist + (size_t)b * NBUCK;
  uint32_t sum = 0;
  for (int k = 0; k < 256; k++) sum += h[t * 256 + k];
  csum[t] = sum;
  __syncthreads();
  if (t == 0) {
    uint32_t cum = 0;
    int tc = 0;
    for (int c = 255; c >= 0; c--) {
      if (cum + csum[c] >= PRE_NMS) { tc = c; break; }
      cum += csum[c];
    }
    s_tc = tc;
    s_cum = cum;
  }
  __syncthreads();
  cbuck[t] = h[s_tc * 256 + t];
  __syncthreads();
  if (t == 0) {
    uint32_t cum = s_cum;
    int beta = s_tc * 256;
    for (int d = 255; d >= 0; d--) {
      if (cum + cbuck[d] >= PRE_NMS) { beta = s_tc * 256 + d; break; }
      cum += cbuck[d];
    }
    thresh[b] = (uint32_t)beta;
    cnts[b * 2] = 0;      // strict-above count
    cnts[b * 2 + 1] = 0;  // in-bucket (tie) count
  }
}

// K4: gather candidates. Strictly-above elements fill slots [0, c1) (c1 < 2000
// guaranteed); threshold-bucket ties fill from slot CAP-1 downward (overflow
// ties dropped — only possible in the degenerate all--inf case, harmless since
// -inf entries always output zeros).
__global__ void k_gather(const uint32_t* __restrict__ keys,
                         const float4* __restrict__ anchors,
                         const float4* __restrict__ deltas,
                         const uint32_t* __restrict__ thresh,
                         uint32_t* __restrict__ cnts,
                         unsigned long long* __restrict__ cand_sort,
                         float4* __restrict__ cand_box,
                         int A, int BA) {
  int i = blockIdx.x * blockDim.x + threadIdx.x;
  if (i >= BA) return;
  int b = i / A;
  int a = i - b * A;
  uint32_t k = keys[i];
  uint32_t beta = thresh[b];
  uint32_t bk = k >> 16;
  if (bk < beta) return;
  int pos;
  if (bk > beta) {
    pos = (int)atomicAdd(&cnts[b * 2], 1u);
    if (pos >= PRE_NMS) return;  // defensive; cannot happen
  } else {
    uint32_t p2 = atomicAdd(&cnts[b * 2 + 1], 1u);
    pos = CAP - 1 - (int)p2;
    if (pos < PRE_NMS) return;  // drop overflow ties
  }
  float4 box = decode_clip(anchors[a], deltas[i]);
  size_t o = (size_t)b * CAP + pos;
  // sort key: (score_key desc, anchor index asc) via descending u64 sort
  cand_sort[o] = ((unsigned long long)k << 32) | (uint32_t)(~(uint32_t)a);
  cand_box[o] = box;
}

// K5: one block per batch — bitonic sort CAP u64 keys (desc) with payload,
// emit exact stable top-SEL selection (score + clipped box), -inf padded.
__global__ void __launch_bounds__(512) k_sortsel(
    const uint32_t* __restrict__ cnts,
    const unsigned long long* __restrict__ cand_sort,
    const float4* __restrict__ cand_box,
    float4* __restrict__ sel_box,
    float* __restrict__ sel_score) {
  int b = blockIdx.x;
  int t = threadIdx.x;
  __shared__ unsigned long long skey[CAP];  // 32 KB
  __shared__ uint32_t spay[CAP];            // 16 KB
  uint32_t c1 = cnts[b * 2];
  if (c1 > PRE_NMS) c1 = PRE_NMS;
  uint32_t c2 = cnts[b * 2 + 1];
  if (c2 > CAP - PRE_NMS) c2 = CAP - PRE_NMS;
  for (int i = t; i < CAP; i += 512) {
    bool live = (i < (int)c1) || (i >= (int)(CAP - c2));
    skey[i] = live ? cand_sort[(size_t)b * CAP + i] : 0ull;
    spay[i] = (uint32_t)i;
  }
  for (unsigned k = 2; k <= CAP; k <<= 1) {
    for (unsigned j = k >> 1; j > 0; j >>= 1) {
      __syncthreads();
      for (unsigned i = t; i < (unsigned)CAP; i += 512) {
        unsigned ixj = i ^ j;
        if (ixj > i) {
          unsigned long long va = skey[i], vb = skey[ixj];
          bool desc = ((i & k) == 0);
          if (desc ? (va < vb) : (va > vb)) {
            skey[i] = vb;
            skey[ixj] = va;
            uint32_t p = spay[i];
            spay[i] = spay[ixj];
            spay[ixj] = p;
          }
        }
      }
    }
  }
  __syncthreads();
  for (int r = t; r < SEL; r += 512) {
    unsigned long long sk = skey[r];
    uint32_t khi = (uint32_t)(sk >> 32);
    float sc;
    float4 bx;
    if (khi == 0u) {  // pad slot
      sc = -INFINITY;
      bx = make_float4(0.0f, 0.0f, 0.0f, 0.0f);
    } else {
      sc = key2f(khi);
      bx = cand_box[(size_t)b * CAP + spay[r]];
    }
    sel_score[(size_t)b * SEL + r] = sc;
    sel_box[(size_t)b * SEL + r] = bx;
  }
}

// K6: suppression bitmask. mask[b][i][jb] bit jj set iff j = jb*64+jj > i,
// j < PRE_NMS, IoU(box_i, box_j) > NMS_THR.
__global__ void k_nmsmask(const float4* __restrict__ sel_box,
                          unsigned long long* __restrict__ mask) {
  int jb = blockIdx.x;  // col block
  int ib = blockIdx.y;  // row block
  int b = blockIdx.z;
  int t = threadIdx.x;  // 64
  int i = ib * 64 + t;
  if (jb < ib) {  // uniform per block; entire col tile is <= all rows
    if (i < PRE_NMS) mask[((size_t)b * SEL + i) * NW + jb] = 0ull;
    return;
  }
  __shared__ float4 cb[64];
  __shared__ float careb[64];
  int j0 = jb * 64;
  float4 cbx = sel_box[(size_t)b * SEL + j0 + t];
  cb[t] = cbx;
  careb[t] = (cbx.z - cbx.x) * (cbx.w - cbx.y);
  __syncthreads();
  if (i >= PRE_NMS) return;
  float4 a = sel_box[(size_t)b * SEL + i];
  float area_a = (a.z - a.x) * (a.w - a.y);
  unsigned long long bits = 0ull;
  int jmax = min(64, PRE_NMS - j0);
  for (int jj = 0; jj < jmax; jj++) {
    int j = j0 + jj;
    if (j <= i) continue;
    float4 bb = cb[jj];
    float ltx = fmaxf(a.x, bb.x), lty = fmaxf(a.y, bb.y);
    float rbx = fminf(a.z, bb.z), rby = fminf(a.w, bb.w);
    float w = fmaxf(rbx - ltx, 0.0f), hgt = fmaxf(rby - lty, 0.0f);
    float inter = w * hgt;
    float iou = inter / (area_a + careb[jj] - inter + 1e-6f);
    if (iou > NMS_THR) bits |= (1ull << jj);
  }
  mask[((size_t)b * SEL + i) * NW + jb] = bits;
}

// K7: one wave per batch. Serial greedy scan; removed bitmask lives one u64
// per lane (lanes 0..31), keep-bit fetched via shfl (row i's word index is
// exactly i/64 == current chunk). Early exit at POST_NMS kept.
__global__ void k_scanout(const float4* __restrict__ sel_box,
                          const float* __restrict__ sel_score,
                          const unsigned long long* __restrict__ mask,
                          float* __restrict__ out) {
  int b = blockIdx.x;
  int t = threadIdx.x;  // 64 = 1 wave
  __shared__ unsigned long long mrows[64 * NW];  // 16 KB: 64 rows of mask
  __shared__ float sscore[64];
  __shared__ uint32_t keptList[POST_NMS];
  unsigned long long removed = 0ull;
  int kc = 0;
  for (int chunk = 0; chunk < SEL / 64; chunk++) {
    __syncthreads();
    const unsigned long long* src = mask + ((size_t)b * SEL + chunk * 64) * NW;
    for (int q = t; q < 64 * NW; q += 64) mrows[q] = src[q];
    sscore[t] = sel_score[(size_t)b * SEL + chunk * 64 + t];
    __syncthreads();
    for (int r = 0; r < 64; r++) {
      int i = chunk * 64 + r;
      if (i >= PRE_NMS) break;
      unsigned long long rw = __shfl(removed, chunk);  // word i>>6 == chunk
      if (!((rw >> r) & 1ull)) {
        if (t < NW) removed |= mrows[r * NW + t];
        float sc = sscore[r];
        if (sc != -INFINITY) {
          if (t == 0) keptList[kc] = (uint32_t)i;
          kc++;
          if (kc == POST_NMS) goto writeout;
        }
      }
    }
  }
writeout:
  __syncthreads();
  for (int r = t; r < POST_NMS; r += 64) {
    float4 bx = make_float4(0.0f, 0.0f, 0.0f, 0.0f);
    float sc = 0.0f;
    if (r < kc) {
      int i = (int)keptList[r];
      bx = sel_box[(size_t)b * SEL + i];
      sc = sel_score[(size_t)b * SEL + i];
    }
    float* o = out + ((size_t)b * POST_NMS + r) * 5;
    o[0] = bx.x;
    o[1] = bx.y;
    o[2] = bx.z;
    o[3] = bx.w;
    o[4] = sc;
  }
}

extern "C" void kernel_launch(void* const* d_in, const int* in_sizes, int n_in,
                              void* d_out, int out_size, void* d_ws, size_t ws_size,
                              hipStream_t stream) {
  const float* anchors = (const float*)d_in[0];  // (A, 4)
  const float* deltas = (const float*)d_in[1];   // (B, A, 4)
  const float* scores = (const float*)d_in[2];   // (B, A)
  int A = in_sizes[0] / 4;
  int BA = in_sizes[2];
  int B = BA / A;
  float* out = (float*)d_out;

  char* ws = (char*)d_ws;
  size_t off = 0;
  uint32_t* keys = (uint32_t*)(ws + off);
  off += (size_t)BA * 4;
  uint32_t* hist = (uint32_t*)(ws + off);
  off += (size_t)B * NBUCK * 4;
  uint32_t* thresh = (uint32_t*)(ws + off);
  off += (size_t)B * 4;
  uint32_t* cnts = (uint32_t*)(ws + off);
  off += (size_t)B * 8;
  off = (off + 15) & ~(size_t)15;
  unsigned long long* cand_sort = (unsigned long long*)(ws + off);
  off += (size_t)B * CAP * 8;
  float4* cand_box = (float4*)(ws + off);
  off += (size_t)B * CAP * 16;
  float4* sel_box = (float4*)(ws + off);
  off += (size_t)B * SEL * 16;
  float* sel_score = (float*)(ws + off);
  off += (size_t)B * SEL * 4;
  unsigned long long* mask = (unsigned long long*)(ws + off);
  off += (size_t)B * SEL * NW * 8;
  // total ~31.5 MB; assumed <= ws_size

  int nb = (BA + 255) / 256;
  hipMemsetAsync(hist, 0, (size_t)B * NBUCK * 4, stream);
  k_decode_keys<<<nb, 256, 0, stream>>>((const float4*)anchors,
                                        (const float4*)deltas, scores, keys, A,
                                        BA);
  k_hist<<<nb, 256, 0, stream>>>(keys, hist, A, BA);
  k_findthresh<<<B, 256, 0, stream>>>(hist, thresh, cnts);
  k_gather<<<nb, 256, 0, stream>>>(keys, (const float4*)anchors,
                                   (const float4*)deltas, thresh, cnts,
                                   cand_sort, cand_box, A, BA);
  k_sortsel<<<B, 512, 0, stream>>>(cnts, cand_sort, cand_box, sel_box,
                                   sel_score);
  k_nmsmask<<<dim3(NW, SEL / 64, B), 64, 0, stream>>>(sel_box, mask);
  k_scanout<<<B, 64, 0, stream>>>(sel_box, sel_score, mask, out);
}

// Round 2
// 850.722 us; speedup vs baseline: 2.0172x; 2.0172x over previous
//
#include <hip/hip_runtime.h>
#include <stdint.h>
#include <math.h>

// RPN proposal filtering: decode -> clip -> validity mask -> stable top-2000
// -> greedy NMS (IoU > 0.7) -> first 1000 kept -> (B, 1000, 5).
//
// R2: k_gather's contended value-returning atomics (640 us @ 16ns/same-line-RMW)
// replaced by wave-aggregated atomics on 128B-padded counters; decode+hist
// fused; -inf excluded from hist; findthresh scans parallelized; scanout
// critical path rebuilt on v_readlane (scalar) + register-resident mask rows.

#define IMGF 1024.0f
#define PRE_NMS 2000
#define POST_NMS 1000
#define NMS_THR 0.7f
#define MIN_SZ 16.0f
#define CAP 4096          // candidate buffer per batch (power of 2 for bitonic)
#define SEL 2048          // padded selection stride (>= PRE_NMS)
#define NW (SEL / 64)     // 32 mask words per row
#define NBUCK 65536
#define CNT_STRIDE 32     // u32s per batch for counters (128 B -> own cache line)
#define KEY_NEGINF 0x007FFFFFu  // f2key(-inf)

// Order-preserving float -> u32 key (all floats incl. -inf totally ordered).
__device__ __forceinline__ uint32_t f2key(float f) {
  uint32_t u = __float_as_uint(f);
  return (u & 0x80000000u) ? ~u : (u | 0x80000000u);
}
__device__ __forceinline__ float key2f(uint32_t k) {
  uint32_t u = (k & 0x80000000u) ? (k & 0x7FFFFFFFu) : ~k;
  return __uint_as_float(u);
}

__device__ __forceinline__ unsigned long long readlane_u64(unsigned long long v,
                                                           int lane) {
  unsigned int lo = __builtin_amdgcn_readlane((unsigned int)v, lane);
  unsigned int hi = __builtin_amdgcn_readlane((unsigned int)(v >> 32), lane);
  return ((unsigned long long)hi << 32) | lo;
}

// Mirrors reference _decode + clip, fp32.
__device__ __forceinline__ float4 decode_clip(float4 anc, float4 dlt) {
  float aw = anc.z - anc.x;
  float ah = anc.w - anc.y;
  float ax = anc.x + 0.5f * aw;
  float ay = anc.y + 0.5f * ah;
  float dw = fminf(dlt.z, 4.0f);
  float dh = fminf(dlt.w, 4.0f);
  float px = dlt.x * aw + ax;
  float py = dlt.y * ah + ay;
  float pw = expf(dw) * aw;
  float ph = expf(dh) * ah;
  float x1 = px - 0.5f * pw, y1 = py - 0.5f * ph;
  float x2 = px + 0.5f * pw, y2 = py + 0.5f * ph;
  x1 = fminf(fmaxf(x1, 0.0f), IMGF);
  y1 = fminf(fmaxf(y1, 0.0f), IMGF);
  x2 = fminf(fmaxf(x2, 0.0f), IMGF);
  y2 = fminf(fmaxf(y2, 0.0f), IMGF);
  return make_float4(x1, y1, x2, y2);
}

// K1: decode -> masked-score key, fused 16-bit-bucket histogram.
// -inf keys excluded from hist (removes the hot invalid bucket; threshold
// search never needs them while >=2000 finite entries exist; beta=0 fallback
// covers the degenerate case).
__global__ void k_decode_hist(const float4* __restrict__ anchors,
                              const float4* __restrict__ deltas,
                              const float* __restrict__ scores,
                              uint32_t* __restrict__ keys,
                              uint32_t* __restrict__ hist,
                              int A, int BA) {
  int i = blockIdx.x * blockDim.x + threadIdx.x;
  if (i >= BA) return;
  int b = i / A;
  int a = i - b * A;
  float4 box = decode_clip(anchors[a], deltas[i]);
  bool valid = (box.z - box.x >= MIN_SZ) && (box.w - box.y >= MIN_SZ);
  float ms = valid ? scores[i] : -INFINITY;
  uint32_t k = f2key(ms);
  keys[i] = k;
  if (k != KEY_NEGINF)
    atomicAdd(&hist[(size_t)b * NBUCK + (k >> 16)], 1u);
}

// K2: find bucket beta s.t. count(key>>16 >= beta) >= PRE_NMS > count(>= beta+1)
// over finite keys. Parallel suffix scans (no serial t==0 loops).
__global__ void k_findthresh(const uint32_t* __restrict__ hist,
                             uint32_t* __restrict__ thresh,
                             uint32_t* __restrict__ cnts) {
  int b = blockIdx.x;
  int t = threadIdx.x;  // 256
  __shared__ uint32_t sA[256];
  __shared__ int s_tc;
  __shared__ uint32_t s_cum;
  if (t == 0) s_tc = -1;
  const uint32_t* h = hist + (size_t)b * NBUCK;
  uint32_t sum = 0;
  for (int kk = 0; kk < 256; kk++) sum += h[t * 256 + kk];
  sA[t] = sum;
  for (int d = 1; d < 256; d <<= 1) {  // inclusive suffix scan
    __syncthreads();
    uint32_t v = sA[t] + ((t + d < 256) ? sA[t + d] : 0u);
    __syncthreads();
    sA[t] = v;
  }
  __syncthreads();
  uint32_t nxt = (t < 255) ? sA[t + 1] : 0u;
  if (sA[t] >= PRE_NMS && nxt < PRE_NMS) {
    s_tc = t;
    s_cum = nxt;  // count strictly above bucket group t
  }
  __syncthreads();
  int tc = s_tc;
  if (t < 2) cnts[b * CNT_STRIDE + t] = 0;
  if (tc < 0) {  // fewer than PRE_NMS finite entries: take everything finite
    if (t == 0) thresh[b] = 0u;
    return;
  }
  uint32_t cumAbove = s_cum;
  __syncthreads();
  sA[t] = h[tc * 256 + t];
  for (int d = 1; d < 256; d <<= 1) {
    __syncthreads();
    uint32_t v = sA[t] + ((t + d < 256) ? sA[t + d] : 0u);
    __syncthreads();
    sA[t] = v;
  }
  __syncthreads();
  nxt = (t < 255) ? sA[t + 1] : 0u;
  if (cumAbove + sA[t] >= PRE_NMS && cumAbove + nxt < PRE_NMS)
    thresh[b] = (uint32_t)(tc * 256 + t);
}

// K3: gather candidates with WAVE-AGGREGATED atomics (one value-returning
// atomicAdd per wave per category, by lane 0; per-lane slot via ballot prefix).
// Counters padded to 128 B per batch. Strictly-above fills [0, c1) (c1 < 2000
// guaranteed by threshold defn); ties fill from CAP-1 downward; overflow ties
// dropped (only affects never-output slots).
__global__ void k_gather(const uint32_t* __restrict__ keys,
                         const float4* __restrict__ anchors,
                         const float4* __restrict__ deltas,
                         const uint32_t* __restrict__ thresh,
                         uint32_t* __restrict__ cnts,
                         unsigned long long* __restrict__ cand_sort,
                         float4* __restrict__ cand_box,
                         int A, int BA) {
  int i = blockIdx.x * blockDim.x + threadIdx.x;
  bool inb = i < BA;
  int ic = inb ? i : (BA - 1);
  int b = ic / A;
  int a = ic - b * A;
  uint32_t k = keys[ic];
  uint32_t beta = thresh[b];
  uint32_t bk = k >> 16;
  bool above = inb && (bk > beta) && (k != KEY_NEGINF);
  bool tie = inb && (bk == beta) && (k != KEY_NEGINF);
  int lane = threadIdx.x & 63;
  int b0 = __shfl(b, 0);
  bool sameb = (b == b0);  // always true here: A % 64 == 0 (261888/64 = 4092)
  unsigned long long mA = __ballot(above && sameb);
  unsigned long long mT = __ballot(tie && sameb);
  uint32_t baseA = 0, baseT = 0;
  if (lane == 0) {
    if (mA) baseA = atomicAdd(&cnts[b0 * CNT_STRIDE + 0], (uint32_t)__popcll(mA));
    if (mT) baseT = atomicAdd(&cnts[b0 * CNT_STRIDE + 1], (uint32_t)__popcll(mT));
  }
  baseA = (uint32_t)__shfl((int)baseA, 0);
  baseT = (uint32_t)__shfl((int)baseT, 0);
  if (!(above || tie)) return;
  unsigned long long lower = ((unsigned long long)1 << lane) - 1;
  int pos;
  if (sameb) {
    if (above)
      pos = (int)(baseA + __popcll(mA & lower));
    else
      pos = CAP - 1 - (int)(baseT + __popcll(mT & lower));
  } else {  // straddling-wave fallback (unreachable for A % 64 == 0)
    if (above)
      pos = (int)atomicAdd(&cnts[b * CNT_STRIDE + 0], 1u);
    else
      pos = CAP - 1 - (int)atomicAdd(&cnts[b * CNT_STRIDE + 1], 1u);
  }
  if (above && pos >= PRE_NMS) return;   // defensive; cannot happen
  if (!above && pos < PRE_NMS) return;   // drop overflow ties
  float4 box = decode_clip(anchors[a], deltas[ic]);
  size_t o = (size_t)b * CAP + pos;
  // sort key: (score_key desc, anchor index asc) via descending u64 sort
  cand_sort[o] = ((unsigned long long)k << 32) | (uint32_t)(~(uint32_t)a);
  cand_box[o] = box;
}

// K4: one block per batch — bitonic sort CAP u64 keys (desc) with payload,
// emit exact stable top-SEL selection (score + clipped box), -inf padded.
__global__ void __launch_bounds__(512) k_sortsel(
    const uint32_t* __restrict__ cnts,
    const unsigned long long* __restrict__ cand_sort,
    const float4* __restrict__ cand_box,
    float4* __restrict__ sel_box,
    float* __restrict__ sel_score) {
  int b = blockIdx.x;
  int t = threadIdx.x;
  __shared__ unsigned long long skey[CAP];  // 32 KB
  __shared__ uint32_t spay[CAP];            // 16 KB
  uint32_t c1 = cnts[b * CNT_STRIDE + 0];
  if (c1 > PRE_NMS) c1 = PRE_NMS;
  uint32_t c2 = cnts[b * CNT_STRIDE + 1];
  if (c2 > CAP - PRE_NMS) c2 = CAP - PRE_NMS;
  for (int i = t; i < CAP; i += 512) {
    bool live = (i < (int)c1) || (i >= (int)(CAP - c2));
    skey[i] = live ? cand_sort[(size_t)b * CAP + i] : 0ull;
    spay[i] = (uint32_t)i;
  }
  for (unsigned k = 2; k <= CAP; k <<= 1) {
    for (unsigned j = k >> 1; j > 0; j >>= 1) {
      __syncthreads();
      for (unsigned i = t; i < (unsigned)CAP; i += 512) {
        unsigned ixj = i ^ j;
        if (ixj > i) {
          unsigned long long va = skey[i], vb = skey[ixj];
          bool desc = ((i & k) == 0);
          if (desc ? (va < vb) : (va > vb)) {
            skey[i] = vb;
            skey[ixj] = va;
            uint32_t p = spay[i];
            spay[i] = spay[ixj];
            spay[ixj] = p;
          }
        }
      }
    }
  }
  __syncthreads();
  for (int r = t; r < SEL; r += 512) {
    unsigned long long sk = skey[r];
    uint32_t khi = (uint32_t)(sk >> 32);
    float sc;
    float4 bx;
    if (khi == 0u) {  // pad slot
      sc = -INFINITY;
      bx = make_float4(0.0f, 0.0f, 0.0f, 0.0f);
    } else {
      sc = key2f(khi);
      bx = cand_box[(size_t)b * CAP + spay[r]];
    }
    sel_score[(size_t)b * SEL + r] = sc;
    sel_box[(size_t)b * SEL + r] = bx;
  }
}

// K5: suppression bitmask. mask[b][i][jb] bit jj set iff j = jb*64+jj > i,
// j < PRE_NMS, IoU(box_i, box_j) > NMS_THR. Rows >= PRE_NMS never written
// (never consumed meaningfully either — see k_scanout analysis).
__global__ void k_nmsmask(const float4* __restrict__ sel_box,
                          unsigned long long* __restrict__ mask) {
  int jb = blockIdx.x;  // col block
  int ib = blockIdx.y;  // row block
  int b = blockIdx.z;
  int t = threadIdx.x;  // 64
  int i = ib * 64 + t;
  if (jb < ib) {  // uniform per block; entire col tile is <= all rows
    if (i < PRE_NMS) mask[((size_t)b * SEL + i) * NW + jb] = 0ull;
    return;
  }
  __shared__ float4 cb[64];
  __shared__ float careb[64];
  int j0 = jb * 64;
  float4 cbx = sel_box[(size_t)b * SEL + j0 + t];
  cb[t] = cbx;
  careb[t] = (cbx.z - cbx.x) * (cbx.w - cbx.y);
  __syncthreads();
  if (i >= PRE_NMS) return;
  float4 a = sel_box[(size_t)b * SEL + i];
  float area_a = (a.z - a.x) * (a.w - a.y);
  unsigned long long bits = 0ull;
  int jmax = min(64, PRE_NMS - j0);
  for (int jj = 0; jj < jmax; jj++) {
    int j = j0 + jj;
    if (j <= i) continue;
    float4 bb = cb[jj];
    float ltx = fmaxf(a.x, bb.x), lty = fmaxf(a.y, bb.y);
    float rbx = fminf(a.z, bb.z), rby = fminf(a.w, bb.w);
    float w = fmaxf(rbx - ltx, 0.0f), hgt = fmaxf(rby - lty, 0.0f);
    float inter = w * hgt;
    float iou = inter / (area_a + careb[jj] - inter + 1e-6f);
    if (iou > NMS_THR) bits |= (1ull << jj);
  }
  mask[((size_t)b * SEL + i) * NW + jb] = bits;
}

// K6: one wave per batch. Serial greedy scan. `removed` word w lives in lane
// w's register (w<32); current chunk's word broadcast via v_readlane (scalar,
// ~VALU latency — no LDS/shfl on the critical path). Mask rows prefetched 16
// at a time into registers, double-buffered. All branch conditions are
// wave-uniform scalars. Early exit at POST_NMS kept.
// NOTE rows >= PRE_NMS read poisoned mask words; they only ever corrupt
// `removed` bits for later pad rows (score -inf, never counted) — harmless.
__global__ void k_scanout(const float4* __restrict__ sel_box,
                          const float* __restrict__ sel_score,
                          const unsigned long long* __restrict__ mask,
                          float* __restrict__ out) {
  int b = blockIdx.x;
  int t = threadIdx.x;  // 64 = 1 wave
  int tw = t & 31;
  __shared__ uint32_t keptList[POST_NMS];
  unsigned long long removed = 0ull;  // lane w<32 owns word w
  int kc = 0;
  const unsigned long long* mbase = mask + (size_t)b * SEL * NW;
  for (int chunk = 0; chunk < SEL / 64; chunk++) {
    uint32_t scb_all =
        __float_as_uint(sel_score[(size_t)b * SEL + chunk * 64 + t]);
    const unsigned long long* cbase = mbase + (size_t)chunk * 64 * NW;
    unsigned long long curw = readlane_u64(removed, chunk);
    unsigned long long m[16], mn[16];
#pragma unroll
    for (int j = 0; j < 16; j++) m[j] = cbase[j * NW + tw];
    for (int sub = 0; sub < 4; sub++) {
      if (sub < 3) {
#pragma unroll
        for (int j = 0; j < 16; j++)
          mn[j] = cbase[((sub + 1) * 16 + j) * NW + tw];
      }
#pragma unroll
      for (int j = 0; j < 16; j++) {
        int r = sub * 16 + j;
        if (!((curw >> r) & 1ull)) {
          removed |= m[j];
          curw = readlane_u64(removed, chunk);
          uint32_t scb = __builtin_amdgcn_readlane(scb_all, r);
          if (scb != 0xFF800000u) {  // score != -inf
            if (t == 0) keptList[kc] = (uint32_t)(chunk * 64 + r);
            kc++;
            if (kc == POST_NMS) goto writeout;
          }
        }
      }
      if (sub < 3) {
#pragma unroll
        for (int j = 0; j < 16; j++) m[j] = mn[j];
      }
    }
  }
writeout:
  __syncthreads();
  for (int r = t; r < POST_NMS; r += 64) {
    float4 bx = make_float4(0.0f, 0.0f, 0.0f, 0.0f);
    float sc = 0.0f;
    if (r < kc) {
      int i = (int)keptList[r];
      bx = sel_box[(size_t)b * SEL + i];
      sc = sel_score[(size_t)b * SEL + i];
    }
    float* o = out + ((size_t)b * POST_NMS + r) * 5;
    o[0] = bx.x;
    o[1] = bx.y;
    o[2] = bx.z;
    o[3] = bx.w;
    o[4] = sc;
  }
}

extern "C" void kernel_launch(void* const* d_in, const int* in_sizes, int n_in,
                              void* d_out, int out_size, void* d_ws, size_t ws_size,
                              hipStream_t stream) {
  const float* anchors = (const float*)d_in[0];  // (A, 4)
  const float* deltas = (const float*)d_in[1];   // (B, A, 4)
  const float* scores = (const float*)d_in[2];   // (B, A)
  int A = in_sizes[0] / 4;
  int BA = in_sizes[2];
  int B = BA / A;
  float* out = (float*)d_out;

  char* ws = (char*)d_ws;
  size_t off = 0;
  uint32_t* keys = (uint32_t*)(ws + off);
  off += (size_t)BA * 4;
  uint32_t* hist = (uint32_t*)(ws + off);
  off += (size_t)B * NBUCK * 4;
  uint32_t* thresh = (uint32_t*)(ws + off);
  off += (size_t)B * 4;
  off = (off + 127) & ~(size_t)127;
  uint32_t* cnts = (uint32_t*)(ws + off);
  off += (size_t)B * CNT_STRIDE * 4;
  off = (off + 15) & ~(size_t)15;
  unsigned long long* cand_sort = (unsigned long long*)(ws + off);
  off += (size_t)B * CAP * 8;
  float4* cand_box = (float4*)(ws + off);
  off += (size_t)B * CAP * 16;
  float4* sel_box = (float4*)(ws + off);
  off += (size_t)B * SEL * 16;
  float* sel_score = (float*)(ws + off);
  off += (size_t)B * SEL * 4;
  unsigned long long* mask = (unsigned long long*)(ws + off);
  off += (size_t)B * SEL * NW * 8;
  // total ~31.5 MB; assumed <= ws_size

  int nb = (BA + 255) / 256;
  hipMemsetAsync(hist, 0, (size_t)B * NBUCK * 4, stream);
  k_decode_hist<<<nb, 256, 0, stream>>>((const float4*)anchors,
                                        (const float4*)deltas, scores, keys,
                                        hist, A, BA);
  k_findthresh<<<B, 256, 0, stream>>>(hist, thresh, cnts);
  k_gather<<<nb, 256, 0, stream>>>(keys, (const float4*)anchors,
                                   (const float4*)deltas, thresh, cnts,
                                   cand_sort, cand_box, A, BA);
  k_sortsel<<<B, 512, 0, stream>>>(cnts, cand_sort, cand_box, sel_box,
                                   sel_score);
  k_nmsmask<<<dim3(NW, SEL / 64, B), 64, 0, stream>>>(sel_box, mask);
  k_scanout<<<B, 64, 0, stream>>>(sel_box, sel_score, mask, out);
}

// Round 4
// 488.533 us; speedup vs baseline: 3.5127x; 1.7414x over previous
//
#include <hip/hip_runtime.h>
#include <stdint.h>
#include <math.h>

// RPN proposal filtering: decode -> clip -> validity mask -> stable top-2000
// -> greedy NMS (IoU > 0.7) -> first 1000 kept -> (B, 1000, 5).
//
// R4: fix R3's replay divergence. R3 dropped R2's `i >= PRE_NMS` guard in
// k_scanout, letting rank-2001+ candidates (rows 2000..2047 of the padded
// selection, which have finite scores but UNWRITTEN mask rows) enter the
// output whenever kept<1000 — gated by workspace poison => state-dependent
// output. Restored the hard row bound (reference runs NMS over exactly the
// top-2000) and zero-fill mask rows >= PRE_NMS so no uninitialized workspace
// is ever read. Histogram/gather path unchanged from R3.

#define IMGF 1024.0f
#define PRE_NMS 2000
#define POST_NMS 1000
#define NMS_THR 0.7f
#define MIN_SZ 16.0f
#define CAP 4096          // candidate buffer per batch (power of 2 for bitonic)
#define SEL 2048          // padded selection stride (>= PRE_NMS)
#define NW (SEL / 64)     // 32 mask words per row
#define CNT_STRIDE 32     // u32s per batch for counters (128 B -> own line)
#define KEY_NEGINF 0x007FFFFFu  // f2key(-inf)

// Order-preserving float -> u32 key (all floats incl. -inf totally ordered).
__device__ __forceinline__ uint32_t f2key(float f) {
  uint32_t u = __float_as_uint(f);
  return (u & 0x80000000u) ? ~u : (u | 0x80000000u);
}
__device__ __forceinline__ float key2f(uint32_t k) {
  uint32_t u = (k & 0x80000000u) ? (k & 0x7FFFFFFFu) : ~k;
  return __uint_as_float(u);
}

__device__ __forceinline__ unsigned long long readlane_u64(unsigned long long v,
                                                           int lane) {
  unsigned int lo = __builtin_amdgcn_readlane((unsigned int)v, lane);
  unsigned int hi = __builtin_amdgcn_readlane((unsigned int)(v >> 32), lane);
  return ((unsigned long long)hi << 32) | lo;
}

// Mirrors reference _decode + clip, fp32.
__device__ __forceinline__ float4 decode_clip(float4 anc, float4 dlt) {
  float aw = anc.z - anc.x;
  float ah = anc.w - anc.y;
  float ax = anc.x + 0.5f * aw;
  float ay = anc.y + 0.5f * ah;
  float dw = fminf(dlt.z, 4.0f);
  float dh = fminf(dlt.w, 4.0f);
  float px = dlt.x * aw + ax;
  float py = dlt.y * ah + ay;
  float pw = expf(dw) * aw;
  float ph = expf(dh) * ah;
  float x1 = px - 0.5f * pw, y1 = py - 0.5f * ph;
  float x2 = px + 0.5f * pw, y2 = py + 0.5f * ph;
  x1 = fminf(fmaxf(x1, 0.0f), IMGF);
  y1 = fminf(fmaxf(y1, 0.0f), IMGF);
  x2 = fminf(fmaxf(x2, 0.0f), IMGF);
  y2 = fminf(fmaxf(y2, 0.0f), IMGF);
  return make_float4(x1, y1, x2, y2);
}

// K1: decode -> masked-score key; per-block LDS coarse hist of key>>24
// (finite keys only), ballot-match wave aggregation, one aggregated global
// flush per block. grid = (BPB, B); each block handles chunks*256 contiguous
// elements of one batch.
__global__ void k_decode(const float4* __restrict__ anchors,
                         const float4* __restrict__ deltas,
                         const float* __restrict__ scores,
                         uint32_t* __restrict__ keys,
                         uint32_t* __restrict__ chist,
                         int A, int chunks) {
  int b = blockIdx.y;
  int t = threadIdx.x;  // 256
  int lane = t & 63;
  __shared__ uint32_t shist[256];
  shist[t] = 0;
  __syncthreads();
  int base_a = blockIdx.x * (chunks * 256);
  for (int c = 0; c < chunks; c++) {
    int a = base_a + c * 256 + t;
    bool inb = a < A;
    int ac = inb ? a : (A - 1);
    size_t i = (size_t)b * A + ac;
    float4 box = decode_clip(anchors[ac], deltas[i]);
    bool valid = (box.z - box.x >= MIN_SZ) && (box.w - box.y >= MIN_SZ);
    float ms = valid ? scores[i] : -INFINITY;
    uint32_t k = f2key(ms);
    if (inb) keys[i] = k;
    uint32_t bucket = k >> 24;
    bool fin = inb && (k != KEY_NEGINF);
    // lanes with equal bucket -> one LDS atomic by the leader
    unsigned long long match = __ballot(fin);
#pragma unroll
    for (int bit = 0; bit < 8; bit++) {
      bool hb = (bucket >> bit) & 1;
      unsigned long long bb = __ballot(hb && fin);
      match &= hb ? bb : ~bb;
    }
    if (fin && (__ffsll((long long)match) - 1 == lane))
      atomicAdd(&shist[bucket], (uint32_t)__popcll(match));
  }
  __syncthreads();
  uint32_t v = shist[t];
  if (v) atomicAdd(&chist[b * 256 + t], v);
}

// K2: pick coarse bucket cb s.t. countAbove(cb) < PRE_NMS <= countAbove(cb)+chist[cb].
__global__ void k_coarse(const uint32_t* __restrict__ chist,
                         int* __restrict__ cbArr,
                         uint32_t* __restrict__ cumArr) {
  int b = blockIdx.x;
  int t = threadIdx.x;  // 256
  __shared__ uint32_t sA[256];
  sA[t] = chist[b * 256 + t];
  for (int d = 1; d < 256; d <<= 1) {  // inclusive suffix scan
    __syncthreads();
    uint32_t v = sA[t] + ((t + d < 256) ? sA[t + d] : 0u);
    __syncthreads();
    sA[t] = v;
  }
  __syncthreads();
  if (t == 0 && sA[0] < PRE_NMS) {  // degenerate: < PRE_NMS finite entries
    cbArr[b] = -1;
    cumArr[b] = 0;
  }
  uint32_t nxt = (t < 255) ? sA[t + 1] : 0u;
  if (sA[t] >= PRE_NMS && nxt < PRE_NMS) {
    cbArr[b] = t;
    cumArr[b] = nxt;  // count strictly above coarse bucket t
  }
}

// K3: fine hist of key bits[23:16] for elements whose coarse bucket == cb[b].
__global__ void k_fine(const uint32_t* __restrict__ keys,
                       const int* __restrict__ cbArr,
                       uint32_t* __restrict__ fhist,
                       int A, int chunks) {
  int b = blockIdx.y;
  int t = threadIdx.x;  // 256
  int cb = cbArr[b];
  if (cb < 0) return;
  __shared__ uint32_t shist[256];
  shist[t] = 0;
  __syncthreads();
  int base_a = blockIdx.x * (chunks * 256);
  uint32_t cbu = (uint32_t)cb;
  for (int c = 0; c < chunks; c++) {
    int a = base_a + c * 256 + t;
    if (a >= A) break;
    uint32_t k = keys[(size_t)b * A + a];
    if ((k >> 24) == cbu && k != KEY_NEGINF)
      atomicAdd(&shist[(k >> 16) & 0xFFu], 1u);
  }
  __syncthreads();
  uint32_t v = shist[t];
  if (v) atomicAdd(&fhist[b * 256 + t], v);
}

// K4: final 16-bit threshold beta = (cb<<8)|d:
// count(key>>16 > beta) < PRE_NMS <= count(key>>16 >= beta), finite keys only.
__global__ void k_thresh(const uint32_t* __restrict__ fhist,
                         const int* __restrict__ cbArr,
                         const uint32_t* __restrict__ cumArr,
                         uint32_t* __restrict__ thresh,
                         uint32_t* __restrict__ cnts) {
  int b = blockIdx.x;
  int t = threadIdx.x;  // 256
  __shared__ uint32_t sA[256];
  if (t < 2) cnts[b * CNT_STRIDE + t] = 0;
  int cb = cbArr[b];
  if (cb < 0) {
    if (t == 0) thresh[b] = 0u;
    return;
  }
  uint32_t cumAbove = cumArr[b];
  sA[t] = fhist[b * 256 + t];
  for (int d = 1; d < 256; d <<= 1) {
    __syncthreads();
    uint32_t v = sA[t] + ((t + d < 256) ? sA[t + d] : 0u);
    __syncthreads();
    sA[t] = v;
  }
  __syncthreads();
  uint32_t nxt = (t < 255) ? sA[t + 1] : 0u;
  if (cumAbove + sA[t] >= PRE_NMS && cumAbove + nxt < PRE_NMS)
    thresh[b] = (uint32_t)((cb << 8) | t);
}

// K5: gather candidates with wave-aggregated atomics (one value-returning
// atomicAdd per wave per category; per-lane slot via ballot prefix).
// Strictly-above fills [0, c1) (c1 < 2000 by threshold defn); ties fill from
// CAP-1 downward; overflow ties dropped (only affects never-output slots).
__global__ void k_gather(const uint32_t* __restrict__ keys,
                         const float4* __restrict__ anchors,
                         const float4* __restrict__ deltas,
                         const uint32_t* __restrict__ thresh,
                         uint32_t* __restrict__ cnts,
                         unsigned long long* __restrict__ cand_sort,
                         float4* __restrict__ cand_box,
                         int A, int BA) {
  int i = blockIdx.x * blockDim.x + threadIdx.x;
  bool inb = i < BA;
  int ic = inb ? i : (BA - 1);
  int b = ic / A;
  int a = ic - b * A;
  uint32_t k = keys[ic];
  uint32_t beta = thresh[b];
  uint32_t bk = k >> 16;
  bool above = inb && (bk > beta) && (k != KEY_NEGINF);
  bool tie = inb && (bk == beta) && (k != KEY_NEGINF);
  int lane = threadIdx.x & 63;
  int b0 = __shfl(b, 0);
  bool sameb = (b == b0);  // always true here: A % 64 == 0
  unsigned long long mA = __ballot(above && sameb);
  unsigned long long mT = __ballot(tie && sameb);
  uint32_t baseA = 0, baseT = 0;
  if (lane == 0) {
    if (mA) baseA = atomicAdd(&cnts[b0 * CNT_STRIDE + 0], (uint32_t)__popcll(mA));
    if (mT) baseT = atomicAdd(&cnts[b0 * CNT_STRIDE + 1], (uint32_t)__popcll(mT));
  }
  baseA = (uint32_t)__shfl((int)baseA, 0);
  baseT = (uint32_t)__shfl((int)baseT, 0);
  if (!(above || tie)) return;
  unsigned long long lower = ((unsigned long long)1 << lane) - 1;
  int pos;
  if (sameb) {
    if (above)
      pos = (int)(baseA + __popcll(mA & lower));
    else
      pos = CAP - 1 - (int)(baseT + __popcll(mT & lower));
  } else {  // straddling-wave fallback (unreachable for A % 64 == 0)
    if (above)
      pos = (int)atomicAdd(&cnts[b * CNT_STRIDE + 0], 1u);
    else
      pos = CAP - 1 - (int)atomicAdd(&cnts[b * CNT_STRIDE + 1], 1u);
  }
  if (above && pos >= PRE_NMS) return;   // defensive; cannot happen
  if (!above && pos < PRE_NMS) return;   // drop overflow ties
  float4 box = decode_clip(anchors[a], deltas[ic]);
  size_t o = (size_t)b * CAP + pos;
  // sort key: (score_key desc, anchor index asc) via descending u64 sort
  cand_sort[o] = ((unsigned long long)k << 32) | (uint32_t)(~(uint32_t)a);
  cand_box[o] = box;
}

// K6: one block per batch — bitonic sort CAP u64 keys (desc) with payload,
// emit exact stable top-SEL selection (score + clipped box), -inf padded.
__global__ void __launch_bounds__(512) k_sortsel(
    const uint32_t* __restrict__ cnts,
    const unsigned long long* __restrict__ cand_sort,
    const float4* __restrict__ cand_box,
    float4* __restrict__ sel_box,
    float* __restrict__ sel_score) {
  int b = blockIdx.x;
  int t = threadIdx.x;
  __shared__ unsigned long long skey[CAP];  // 32 KB
  __shared__ uint32_t spay[CAP];            // 16 KB
  uint32_t c1 = cnts[b * CNT_STRIDE + 0];
  if (c1 > PRE_NMS) c1 = PRE_NMS;
  uint32_t c2 = cnts[b * CNT_STRIDE + 1];
  if (c2 > CAP - PRE_NMS) c2 = CAP - PRE_NMS;
  for (int i = t; i < CAP; i += 512) {
    bool live = (i < (int)c1) || (i >= (int)(CAP - c2));
    skey[i] = live ? cand_sort[(size_t)b * CAP + i] : 0ull;
    spay[i] = (uint32_t)i;
  }
  for (unsigned k = 2; k <= CAP; k <<= 1) {
    for (unsigned j = k >> 1; j > 0; j >>= 1) {
      __syncthreads();
      for (unsigned i = t; i < (unsigned)CAP; i += 512) {
        unsigned ixj = i ^ j;
        if (ixj > i) {
          unsigned long long va = skey[i], vb = skey[ixj];
          bool desc = ((i & k) == 0);
          if (desc ? (va < vb) : (va > vb)) {
            skey[i] = vb;
            skey[ixj] = va;
            uint32_t p = spay[i];
            spay[i] = spay[ixj];
            spay[ixj] = p;
          }
        }
      }
    }
  }
  __syncthreads();
  for (int r = t; r < SEL; r += 512) {
    unsigned long long sk = skey[r];
    uint32_t khi = (uint32_t)(sk >> 32);
    float sc;
    float4 bx;
    if (khi == 0u) {  // pad slot
      sc = -INFINITY;
      bx = make_float4(0.0f, 0.0f, 0.0f, 0.0f);
    } else {
      sc = key2f(khi);
      bx = cand_box[(size_t)b * CAP + spay[r]];
    }
    sel_score[(size_t)b * SEL + r] = sc;
    sel_box[(size_t)b * SEL + r] = bx;
  }
}

// K7: suppression bitmask. mask[b][i][jb] bit jj set iff j = jb*64+jj > i,
// j < PRE_NMS, IoU(box_i, box_j) > NMS_THR. Rows in [PRE_NMS, SEL) are
// ZEROED (R4) so k_scanout never reads unwritten workspace.
__global__ void k_nmsmask(const float4* __restrict__ sel_box,
                          unsigned long long* __restrict__ mask) {
  int jb = blockIdx.x;  // col block
  int ib = blockIdx.y;  // row block
  int b = blockIdx.z;
  int t = threadIdx.x;  // 64
  int i = ib * 64 + t;
  if (jb < ib) {  // uniform per block; entire col tile is <= all rows
    mask[((size_t)b * SEL + i) * NW + jb] = 0ull;
    return;
  }
  __shared__ float4 cb[64];
  __shared__ float careb[64];
  int j0 = jb * 64;
  float4 cbx = sel_box[(size_t)b * SEL + j0 + t];
  cb[t] = cbx;
  careb[t] = (cbx.z - cbx.x) * (cbx.w - cbx.y);
  __syncthreads();
  if (i >= PRE_NMS) {  // pad rows: write zeros, never leave stale poison
    mask[((size_t)b * SEL + i) * NW + jb] = 0ull;
    return;
  }
  float4 a = sel_box[(size_t)b * SEL + i];
  float area_a = (a.z - a.x) * (a.w - a.y);
  unsigned long long bits = 0ull;
  int jmax = min(64, PRE_NMS - j0);
  for (int jj = 0; jj < jmax; jj++) {
    int j = j0 + jj;
    if (j <= i) continue;
    float4 bb = cb[jj];
    float ltx = fmaxf(a.x, bb.x), lty = fmaxf(a.y, bb.y);
    float rbx = fminf(a.z, bb.z), rby = fminf(a.w, bb.w);
    float w = fmaxf(rbx - ltx, 0.0f), hgt = fmaxf(rby - lty, 0.0f);
    float inter = w * hgt;
    float iou = inter / (area_a + careb[jj] - inter + 1e-6f);
    if (iou > NMS_THR) bits |= (1ull << jj);
  }
  mask[((size_t)b * SEL + i) * NW + jb] = bits;
}

// K8: one wave per batch. Serial greedy scan over EXACTLY PRE_NMS rows
// (rmax guard restored in R4 — rank-2001+ rows must never be kept/counted).
// removed word w in lane w's register; chunk word broadcast via v_readlane;
// rows prefetched 16-at-a-time into registers (double-buffered); wave-uniform
// scalar branches; early exit at POST_NMS.
__global__ void k_scanout(const float4* __restrict__ sel_box,
                          const float* __restrict__ sel_score,
                          const unsigned long long* __restrict__ mask,
                          float* __restrict__ out) {
  int b = blockIdx.x;
  int t = threadIdx.x;  // 64 = 1 wave
  int tw = t & 31;
  __shared__ uint32_t keptList[POST_NMS];
  unsigned long long removed = 0ull;  // lane w<32 owns word w
  int kc = 0;
  const unsigned long long* mbase = mask + (size_t)b * SEL * NW;
  for (int chunk = 0; chunk < SEL / 64; chunk++) {
    int rmax = PRE_NMS - chunk * 64;  // rows beyond PRE_NMS excluded
    if (rmax <= 0) break;
    if (rmax > 64) rmax = 64;
    uint32_t scb_all =
        __float_as_uint(sel_score[(size_t)b * SEL + chunk * 64 + t]);
    const unsigned long long* cbase = mbase + (size_t)chunk * 64 * NW;
    unsigned long long curw = readlane_u64(removed, chunk);
    unsigned long long m[16], mn[16];
#pragma unroll
    for (int j = 0; j < 16; j++) m[j] = cbase[j * NW + tw];
    for (int sub = 0; sub < 4; sub++) {
      if (sub < 3) {
#pragma unroll
        for (int j = 0; j < 16; j++)
          mn[j] = cbase[((sub + 1) * 16 + j) * NW + tw];
      }
#pragma unroll
      for (int j = 0; j < 16; j++) {
        int r = sub * 16 + j;
        if (r < rmax && !((curw >> r) & 1ull)) {
          removed |= m[j];
          curw = readlane_u64(removed, chunk);
          uint32_t scb = __builtin_amdgcn_readlane(scb_all, r);
          if (scb != 0xFF800000u) {  // score != -inf
            if (t == 0) keptList[kc] = (uint32_t)(chunk * 64 + r);
            kc++;
            if (kc == POST_NMS) goto writeout;
          }
        }
      }
      if (sub < 3) {
#pragma unroll
        for (int j = 0; j < 16; j++) m[j] = mn[j];
      }
    }
  }
writeout:
  __syncthreads();
  for (int r = t; r < POST_NMS; r += 64) {
    float4 bx = make_float4(0.0f, 0.0f, 0.0f, 0.0f);
    float sc = 0.0f;
    if (r < kc) {
      int i = (int)keptList[r];
      bx = sel_box[(size_t)b * SEL + i];
      sc = sel_score[(size_t)b * SEL + i];
    }
    float* o = out + ((size_t)b * POST_NMS + r) * 5;
    o[0] = bx.x;
    o[1] = bx.y;
    o[2] = bx.z;
    o[3] = bx.w;
    o[4] = sc;
  }
}

extern "C" void kernel_launch(void* const* d_in, const int* in_sizes, int n_in,
                              void* d_out, int out_size, void* d_ws, size_t ws_size,
                              hipStream_t stream) {
  const float* anchors = (const float*)d_in[0];  // (A, 4)
  const float* deltas = (const float*)d_in[1];   // (B, A, 4)
  const float* scores = (const float*)d_in[2];   // (B, A)
  int A = in_sizes[0] / 4;
  int BA = in_sizes[2];
  int B = BA / A;
  float* out = (float*)d_out;

  char* ws = (char*)d_ws;
  size_t off = 0;
  uint32_t* keys = (uint32_t*)(ws + off);
  off += (size_t)BA * 4;
  uint32_t* chist = (uint32_t*)(ws + off);
  off += (size_t)B * 256 * 4;
  uint32_t* fhist = (uint32_t*)(ws + off);
  off += (size_t)B * 256 * 4;
  int* cbArr = (int*)(ws + off);
  off += (size_t)B * 4;
  uint32_t* cumArr = (uint32_t*)(ws + off);
  off += (size_t)B * 4;
  uint32_t* thresh = (uint32_t*)(ws + off);
  off += (size_t)B * 4;
  off = (off + 127) & ~(size_t)127;
  uint32_t* cnts = (uint32_t*)(ws + off);
  off += (size_t)B * CNT_STRIDE * 4;
  off = (off + 15) & ~(size_t)15;
  unsigned long long* cand_sort = (unsigned long long*)(ws + off);
  off += (size_t)B * CAP * 8;
  float4* cand_box = (float4*)(ws + off);
  off += (size_t)B * CAP * 16;
  float4* sel_box = (float4*)(ws + off);
  off += (size_t)B * SEL * 16;
  float* sel_score = (float*)(ws + off);
  off += (size_t)B * SEL * 4;
  unsigned long long* mask = (unsigned long long*)(ws + off);
  off += (size_t)B * SEL * NW * 8;
  // total ~28 MB

  // Block geometry for hist kernels: A = 261888 = 256*11*93 -> chunks=11.
  int chunks = (A % (256 * 11) == 0) ? 11 : 1;
  int bpb = (A + 256 * chunks - 1) / (256 * chunks);  // blocks per batch

  hipMemsetAsync(chist, 0, (size_t)B * 256 * 4 * 2, stream);  // chist+fhist
  k_decode<<<dim3(bpb, B), 256, 0, stream>>>((const float4*)anchors,
                                             (const float4*)deltas, scores,
                                             keys, chist, A, chunks);
  k_coarse<<<B, 256, 0, stream>>>(chist, cbArr, cumArr);
  k_fine<<<dim3(bpb, B), 256, 0, stream>>>(keys, cbArr, fhist, A, chunks);
  k_thresh<<<B, 256, 0, stream>>>(fhist, cbArr, cumArr, thresh, cnts);
  int nb = (BA + 255) / 256;
  k_gather<<<nb, 256, 0, stream>>>(keys, (const float4*)anchors,
                                   (const float4*)deltas, thresh, cnts,
                                   cand_sort, cand_box, A, BA);
  k_sortsel<<<B, 512, 0, stream>>>(cnts, cand_sort, cand_box, sel_box,
                                   sel_score);
  k_nmsmask<<<dim3(NW, SEL / 64, B), 64, 0, stream>>>(sel_box, mask);
  k_scanout<<<B, 64, 0, stream>>>(sel_box, sel_score, mask, out);
}

// Round 5
// 400.274 us; speedup vs baseline: 4.2872x; 1.2205x over previous
//
#include <hip/hip_runtime.h>
#include <stdint.h>
#include <math.h>

// RPN proposal filtering: decode -> clip -> validity mask -> stable top-2000
// -> greedy NMS (IoU > 0.7) -> first 1000 kept -> (B, 1000, 5).
//
// R5: k_gather (116 us, ~2400 same-line value-returning atomic RMWs per batch
// at wave granularity) restructured to block-aggregated placement: per-chunk
// ballots in LDS + ONE atomicAdd per category per block (93 blocks/batch ->
// ~93 RMWs/line), deterministic in-block prefix for slots. Slot permutation
// varies with block atomic order but k_sortsel's strict total order
// (score_key, ~anchor) makes the sorted selection run-invariant.

#define IMGF 1024.0f
#define PRE_NMS 2000
#define POST_NMS 1000
#define NMS_THR 0.7f
#define MIN_SZ 16.0f
#define CAP 4096          // candidate buffer per batch (power of 2 for bitonic)
#define SEL 2048          // padded selection stride (>= PRE_NMS)
#define NW (SEL / 64)     // 32 mask words per row
#define CNT_STRIDE 32     // u32s per batch for counters (128 B -> own line)
#define KEY_NEGINF 0x007FFFFFu  // f2key(-inf)
#define MAXCHUNK 12

// Order-preserving float -> u32 key (all floats incl. -inf totally ordered).
__device__ __forceinline__ uint32_t f2key(float f) {
  uint32_t u = __float_as_uint(f);
  return (u & 0x80000000u) ? ~u : (u | 0x80000000u);
}
__device__ __forceinline__ float key2f(uint32_t k) {
  uint32_t u = (k & 0x80000000u) ? (k & 0x7FFFFFFFu) : ~k;
  return __uint_as_float(u);
}

__device__ __forceinline__ unsigned long long readlane_u64(unsigned long long v,
                                                           int lane) {
  unsigned int lo = __builtin_amdgcn_readlane((unsigned int)v, lane);
  unsigned int hi = __builtin_amdgcn_readlane((unsigned int)(v >> 32), lane);
  return ((unsigned long long)hi << 32) | lo;
}

// Mirrors reference _decode + clip, fp32.
__device__ __forceinline__ float4 decode_clip(float4 anc, float4 dlt) {
  float aw = anc.z - anc.x;
  float ah = anc.w - anc.y;
  float ax = anc.x + 0.5f * aw;
  float ay = anc.y + 0.5f * ah;
  float dw = fminf(dlt.z, 4.0f);
  float dh = fminf(dlt.w, 4.0f);
  float px = dlt.x * aw + ax;
  float py = dlt.y * ah + ay;
  float pw = expf(dw) * aw;
  float ph = expf(dh) * ah;
  float x1 = px - 0.5f * pw, y1 = py - 0.5f * ph;
  float x2 = px + 0.5f * pw, y2 = py + 0.5f * ph;
  x1 = fminf(fmaxf(x1, 0.0f), IMGF);
  y1 = fminf(fmaxf(y1, 0.0f), IMGF);
  x2 = fminf(fmaxf(x2, 0.0f), IMGF);
  y2 = fminf(fmaxf(y2, 0.0f), IMGF);
  return make_float4(x1, y1, x2, y2);
}

// K1: decode -> masked-score key; per-block LDS coarse hist of key>>24
// (finite keys only), ballot-match wave aggregation, one aggregated global
// flush per block. grid = (bpb, B); each block handles chunks*256 contiguous
// elements of one batch.
__global__ void k_decode(const float4* __restrict__ anchors,
                         const float4* __restrict__ deltas,
                         const float* __restrict__ scores,
                         uint32_t* __restrict__ keys,
                         uint32_t* __restrict__ chist,
                         int A, int chunks) {
  int b = blockIdx.y;
  int t = threadIdx.x;  // 256
  int lane = t & 63;
  __shared__ uint32_t shist[256];
  shist[t] = 0;
  __syncthreads();
  int base_a = blockIdx.x * (chunks * 256);
  for (int c = 0; c < chunks; c++) {
    int a = base_a + c * 256 + t;
    bool inb = a < A;
    int ac = inb ? a : (A - 1);
    size_t i = (size_t)b * A + ac;
    float4 box = decode_clip(anchors[ac], deltas[i]);
    bool valid = (box.z - box.x >= MIN_SZ) && (box.w - box.y >= MIN_SZ);
    float ms = valid ? scores[i] : -INFINITY;
    uint32_t k = f2key(ms);
    if (inb) keys[i] = k;
    uint32_t bucket = k >> 24;
    bool fin = inb && (k != KEY_NEGINF);
    // lanes with equal bucket -> one LDS atomic by the leader
    unsigned long long match = __ballot(fin);
#pragma unroll
    for (int bit = 0; bit < 8; bit++) {
      bool hb = (bucket >> bit) & 1;
      unsigned long long bb = __ballot(hb && fin);
      match &= hb ? bb : ~bb;
    }
    if (fin && (__ffsll((long long)match) - 1 == lane))
      atomicAdd(&shist[bucket], (uint32_t)__popcll(match));
  }
  __syncthreads();
  uint32_t v = shist[t];
  if (v) atomicAdd(&chist[b * 256 + t], v);
}

// K2: pick coarse bucket cb s.t. countAbove(cb) < PRE_NMS <= countAbove(cb)+chist[cb].
__global__ void k_coarse(const uint32_t* __restrict__ chist,
                         int* __restrict__ cbArr,
                         uint32_t* __restrict__ cumArr) {
  int b = blockIdx.x;
  int t = threadIdx.x;  // 256
  __shared__ uint32_t sA[256];
  sA[t] = chist[b * 256 + t];
  for (int d = 1; d < 256; d <<= 1) {  // inclusive suffix scan
    __syncthreads();
    uint32_t v = sA[t] + ((t + d < 256) ? sA[t + d] : 0u);
    __syncthreads();
    sA[t] = v;
  }
  __syncthreads();
  if (t == 0 && sA[0] < PRE_NMS) {  // degenerate: < PRE_NMS finite entries
    cbArr[b] = -1;
    cumArr[b] = 0;
  }
  uint32_t nxt = (t < 255) ? sA[t + 1] : 0u;
  if (sA[t] >= PRE_NMS && nxt < PRE_NMS) {
    cbArr[b] = t;
    cumArr[b] = nxt;  // count strictly above coarse bucket t
  }
}

// K3: fine hist of key bits[23:16] for elements whose coarse bucket == cb[b].
__global__ void k_fine(const uint32_t* __restrict__ keys,
                       const int* __restrict__ cbArr,
                       uint32_t* __restrict__ fhist,
                       int A, int chunks) {
  int b = blockIdx.y;
  int t = threadIdx.x;  // 256
  int cb = cbArr[b];
  if (cb < 0) return;
  __shared__ uint32_t shist[256];
  shist[t] = 0;
  __syncthreads();
  int base_a = blockIdx.x * (chunks * 256);
  uint32_t cbu = (uint32_t)cb;
  for (int c = 0; c < chunks; c++) {
    int a = base_a + c * 256 + t;
    if (a >= A) break;
    uint32_t k = keys[(size_t)b * A + a];
    if ((k >> 24) == cbu && k != KEY_NEGINF)
      atomicAdd(&shist[(k >> 16) & 0xFFu], 1u);
  }
  __syncthreads();
  uint32_t v = shist[t];
  if (v) atomicAdd(&fhist[b * 256 + t], v);
}

// K4: final 16-bit threshold beta = (cb<<8)|d:
// count(key>>16 > beta) < PRE_NMS <= count(key>>16 >= beta), finite keys only.
__global__ void k_thresh(const uint32_t* __restrict__ fhist,
                         const int* __restrict__ cbArr,
                         const uint32_t* __restrict__ cumArr,
                         uint32_t* __restrict__ thresh,
                         uint32_t* __restrict__ cnts) {
  int b = blockIdx.x;
  int t = threadIdx.x;  // 256
  __shared__ uint32_t sA[256];
  if (t < 2) cnts[b * CNT_STRIDE + t] = 0;
  int cb = cbArr[b];
  if (cb < 0) {
    if (t == 0) thresh[b] = 0u;
    return;
  }
  uint32_t cumAbove = cumArr[b];
  sA[t] = fhist[b * 256 + t];
  for (int d = 1; d < 256; d <<= 1) {
    __syncthreads();
    uint32_t v = sA[t] + ((t + d < 256) ? sA[t + d] : 0u);
    __syncthreads();
    sA[t] = v;
  }
  __syncthreads();
  uint32_t nxt = (t < 255) ? sA[t + 1] : 0u;
  if (cumAbove + sA[t] >= PRE_NMS && cumAbove + nxt < PRE_NMS)
    thresh[b] = (uint32_t)((cb << 8) | t);
}

// K5: gather candidates, block-aggregated. grid = (bpb, B). Phase 1: per-chunk
// ballots (stored in LDS), keys stashed in registers. Single atomicAdd per
// category per block -> ~93 same-line RMWs per batch. Phase 2: deterministic
// in-block slot = base + (chunk,wave) prefix + intra-wave ballot prefix.
// Strictly-above fills [0, c1) (c1 < 2000 by threshold defn); ties fill from
// CAP-1 downward; overflow ties dropped (only possible above 2096 ties/batch).
__global__ void k_gather(const uint32_t* __restrict__ keys,
                         const float4* __restrict__ anchors,
                         const float4* __restrict__ deltas,
                         const uint32_t* __restrict__ thresh,
                         uint32_t* __restrict__ cnts,
                         unsigned long long* __restrict__ cand_sort,
                         float4* __restrict__ cand_box,
                         int A, int chunks) {
  int b = blockIdx.y;
  int t = threadIdx.x;  // 256
  int lane = t & 63;
  int w = t >> 6;  // wave 0..3
  __shared__ unsigned long long s_mA[MAXCHUNK * 4], s_mT[MAXCHUNK * 4];
  __shared__ uint32_t s_offA[MAXCHUNK * 4], s_offT[MAXCHUNK * 4];
  __shared__ uint32_t s_cA[MAXCHUNK * 4], s_cT[MAXCHUNK * 4];
  __shared__ uint32_t s_baseA, s_baseT;
  uint32_t beta = thresh[b];
  uint32_t kreg[MAXCHUNK];
  int base_a = blockIdx.x * (chunks * 256);
  for (int c = 0; c < chunks; c++) {
    int a = base_a + c * 256 + t;
    bool inb = a < A;
    uint32_t k = inb ? keys[(size_t)b * A + a] : KEY_NEGINF;
    kreg[c] = k;
    uint32_t bk = k >> 16;
    bool fin = (k != KEY_NEGINF);
    unsigned long long mA = __ballot(fin && (bk > beta));
    unsigned long long mT = __ballot(fin && (bk == beta));
    if (lane == 0) {
      s_mA[c * 4 + w] = mA;
      s_mT[c * 4 + w] = mT;
    }
  }
  __syncthreads();
  if (t < chunks * 4) {
    s_cA[t] = (uint32_t)__popcll(s_mA[t]);
    s_cT[t] = (uint32_t)__popcll(s_mT[t]);
  }
  __syncthreads();
  if (t == 0) {  // serial scan over <=44 entries, then ONE atomic per category
    uint32_t accA = 0, accT = 0;
    for (int id = 0; id < chunks * 4; id++) {
      s_offA[id] = accA;
      accA += s_cA[id];
      s_offT[id] = accT;
      accT += s_cT[id];
    }
    s_baseA = accA ? atomicAdd(&cnts[b * CNT_STRIDE + 0], accA) : 0u;
    s_baseT = accT ? atomicAdd(&cnts[b * CNT_STRIDE + 1], accT) : 0u;
  }
  __syncthreads();
  uint32_t baseA = s_baseA, baseT = s_baseT;
  unsigned long long lower = ((unsigned long long)1 << lane) - 1;
  for (int c = 0; c < chunks; c++) {
    int id = c * 4 + w;
    unsigned long long mA = s_mA[id], mT = s_mT[id];
    bool above = (mA >> lane) & 1;
    bool tie = (mT >> lane) & 1;
    if (!(above || tie)) continue;
    int pos;
    if (above) {
      pos = (int)(baseA + s_offA[id] + (uint32_t)__popcll(mA & lower));
      if (pos >= PRE_NMS) continue;  // defensive; cannot happen
    } else {
      pos = CAP - 1 - (int)(baseT + s_offT[id] + (uint32_t)__popcll(mT & lower));
      if (pos < PRE_NMS) continue;  // drop overflow ties
    }
    int a = base_a + c * 256 + t;
    size_t i = (size_t)b * A + a;
    float4 box = decode_clip(anchors[a], deltas[i]);
    size_t o = (size_t)b * CAP + pos;
    // sort key: (score_key desc, anchor index asc) via descending u64 sort
    cand_sort[o] = ((unsigned long long)kreg[c] << 32) | (uint32_t)(~(uint32_t)a);
    cand_box[o] = box;
  }
}

// K6: one block per batch — bitonic sort CAP u64 keys (desc) with payload,
// emit exact stable top-SEL selection (score + clipped box), -inf padded.
__global__ void __launch_bounds__(512) k_sortsel(
    const uint32_t* __restrict__ cnts,
    const unsigned long long* __restrict__ cand_sort,
    const float4* __restrict__ cand_box,
    float4* __restrict__ sel_box,
    float* __restrict__ sel_score) {
  int b = blockIdx.x;
  int t = threadIdx.x;
  __shared__ unsigned long long skey[CAP];  // 32 KB
  __shared__ uint32_t spay[CAP];            // 16 KB
  uint32_t c1 = cnts[b * CNT_STRIDE + 0];
  if (c1 > PRE_NMS) c1 = PRE_NMS;
  uint32_t c2 = cnts[b * CNT_STRIDE + 1];
  if (c2 > CAP - PRE_NMS) c2 = CAP - PRE_NMS;
  for (int i = t; i < CAP; i += 512) {
    bool live = (i < (int)c1) || (i >= (int)(CAP - c2));
    skey[i] = live ? cand_sort[(size_t)b * CAP + i] : 0ull;
    spay[i] = (uint32_t)i;
  }
  for (unsigned k = 2; k <= CAP; k <<= 1) {
    for (unsigned j = k >> 1; j > 0; j >>= 1) {
      __syncthreads();
      for (unsigned i = t; i < (unsigned)CAP; i += 512) {
        unsigned ixj = i ^ j;
        if (ixj > i) {
          unsigned long long va = skey[i], vb = skey[ixj];
          bool desc = ((i & k) == 0);
          if (desc ? (va < vb) : (va > vb)) {
            skey[i] = vb;
            skey[ixj] = va;
            uint32_t p = spay[i];
            spay[i] = spay[ixj];
            spay[ixj] = p;
          }
        }
      }
    }
  }
  __syncthreads();
  for (int r = t; r < SEL; r += 512) {
    unsigned long long sk = skey[r];
    uint32_t khi = (uint32_t)(sk >> 32);
    float sc;
    float4 bx;
    if (khi == 0u) {  // pad slot
      sc = -INFINITY;
      bx = make_float4(0.0f, 0.0f, 0.0f, 0.0f);
    } else {
      sc = key2f(khi);
      bx = cand_box[(size_t)b * CAP + spay[r]];
    }
    sel_score[(size_t)b * SEL + r] = sc;
    sel_box[(size_t)b * SEL + r] = bx;
  }
}

// K7: suppression bitmask. mask[b][i][jb] bit jj set iff j = jb*64+jj > i,
// j < PRE_NMS, IoU(box_i, box_j) > NMS_THR. Rows in [PRE_NMS, SEL) zeroed
// so k_scanout never reads unwritten workspace.
__global__ void k_nmsmask(const float4* __restrict__ sel_box,
                          unsigned long long* __restrict__ mask) {
  int jb = blockIdx.x;  // col block
  int ib = blockIdx.y;  // row block
  int b = blockIdx.z;
  int t = threadIdx.x;  // 64
  int i = ib * 64 + t;
  if (jb < ib) {  // uniform per block; entire col tile is <= all rows
    mask[((size_t)b * SEL + i) * NW + jb] = 0ull;
    return;
  }
  __shared__ float4 cb[64];
  __shared__ float careb[64];
  int j0 = jb * 64;
  float4 cbx = sel_box[(size_t)b * SEL + j0 + t];
  cb[t] = cbx;
  careb[t] = (cbx.z - cbx.x) * (cbx.w - cbx.y);
  __syncthreads();
  if (i >= PRE_NMS) {  // pad rows: write zeros, never leave stale poison
    mask[((size_t)b * SEL + i) * NW + jb] = 0ull;
    return;
  }
  float4 a = sel_box[(size_t)b * SEL + i];
  float area_a = (a.z - a.x) * (a.w - a.y);
  unsigned long long bits = 0ull;
  int jmax = min(64, PRE_NMS - j0);
  for (int jj = 0; jj < jmax; jj++) {
    int j = j0 + jj;
    if (j <= i) continue;
    float4 bb = cb[jj];
    float ltx = fmaxf(a.x, bb.x), lty = fmaxf(a.y, bb.y);
    float rbx = fminf(a.z, bb.z), rby = fminf(a.w, bb.w);
    float w = fmaxf(rbx - ltx, 0.0f), hgt = fmaxf(rby - lty, 0.0f);
    float inter = w * hgt;
    float iou = inter / (area_a + careb[jj] - inter + 1e-6f);
    if (iou > NMS_THR) bits |= (1ull << jj);
  }
  mask[((size_t)b * SEL + i) * NW + jb] = bits;
}

// K8: one wave per batch. Serial greedy scan over EXACTLY PRE_NMS rows.
// removed word w in lane w's register; chunk word broadcast via v_readlane;
// rows prefetched 16-at-a-time into registers (double-buffered); wave-uniform
// scalar branches; early exit at POST_NMS.
__global__ void k_scanout(const float4* __restrict__ sel_box,
                          const float* __restrict__ sel_score,
                          const unsigned long long* __restrict__ mask,
                          float* __restrict__ out) {
  int b = blockIdx.x;
  int t = threadIdx.x;  // 64 = 1 wave
  int tw = t & 31;
  __shared__ uint32_t keptList[POST_NMS];
  unsigned long long removed = 0ull;  // lane w<32 owns word w
  int kc = 0;
  const unsigned long long* mbase = mask + (size_t)b * SEL * NW;
  for (int chunk = 0; chunk < SEL / 64; chunk++) {
    int rmax = PRE_NMS - chunk * 64;  // rows beyond PRE_NMS excluded
    if (rmax <= 0) break;
    if (rmax > 64) rmax = 64;
    uint32_t scb_all =
        __float_as_uint(sel_score[(size_t)b * SEL + chunk * 64 + t]);
    const unsigned long long* cbase = mbase + (size_t)chunk * 64 * NW;
    unsigned long long curw = readlane_u64(removed, chunk);
    unsigned long long m[16], mn[16];
#pragma unroll
    for (int j = 0; j < 16; j++) m[j] = cbase[j * NW + tw];
    for (int sub = 0; sub < 4; sub++) {
      if (sub < 3) {
#pragma unroll
        for (int j = 0; j < 16; j++)
          mn[j] = cbase[((sub + 1) * 16 + j) * NW + tw];
      }
#pragma unroll
      for (int j = 0; j < 16; j++) {
        int r = sub * 16 + j;
        if (r < rmax && !((curw >> r) & 1ull)) {
          removed |= m[j];
          curw = readlane_u64(removed, chunk);
          uint32_t scb = __builtin_amdgcn_readlane(scb_all, r);
          if (scb != 0xFF800000u) {  // score != -inf
            if (t == 0) keptList[kc] = (uint32_t)(chunk * 64 + r);
            kc++;
            if (kc == POST_NMS) goto writeout;
          }
        }
      }
      if (sub < 3) {
#pragma unroll
        for (int j = 0; j < 16; j++) m[j] = mn[j];
      }
    }
  }
writeout:
  __syncthreads();
  for (int r = t; r < POST_NMS; r += 64) {
    float4 bx = make_float4(0.0f, 0.0f, 0.0f, 0.0f);
    float sc = 0.0f;
    if (r < kc) {
      int i = (int)keptList[r];
      bx = sel_box[(size_t)b * SEL + i];
      sc = sel_score[(size_t)b * SEL + i];
    }
    float* o = out + ((size_t)b * POST_NMS + r) * 5;
    o[0] = bx.x;
    o[1] = bx.y;
    o[2] = bx.z;
    o[3] = bx.w;
    o[4] = sc;
  }
}

extern "C" void kernel_launch(void* const* d_in, const int* in_sizes, int n_in,
                              void* d_out, int out_size, void* d_ws, size_t ws_size,
                              hipStream_t stream) {
  const float* anchors = (const float*)d_in[0];  // (A, 4)
  const float* deltas = (const float*)d_in[1];   // (B, A, 4)
  const float* scores = (const float*)d_in[2];   // (B, A)
  int A = in_sizes[0] / 4;
  int BA = in_sizes[2];
  int B = BA / A;
  float* out = (float*)d_out;

  char* ws = (char*)d_ws;
  size_t off = 0;
  uint32_t* keys = (uint32_t*)(ws + off);
  off += (size_t)BA * 4;
  uint32_t* chist = (uint32_t*)(ws + off);
  off += (size_t)B * 256 * 4;
  uint32_t* fhist = (uint32_t*)(ws + off);
  off += (size_t)B * 256 * 4;
  int* cbArr = (int*)(ws + off);
  off += (size_t)B * 4;
  uint32_t* cumArr = (uint32_t*)(ws + off);
  off += (size_t)B * 4;
  uint32_t* thresh = (uint32_t*)(ws + off);
  off += (size_t)B * 4;
  off = (off + 127) & ~(size_t)127;
  uint32_t* cnts = (uint32_t*)(ws + off);
  off += (size_t)B * CNT_STRIDE * 4;
  off = (off + 15) & ~(size_t)15;
  unsigned long long* cand_sort = (unsigned long long*)(ws + off);
  off += (size_t)B * CAP * 8;
  float4* cand_box = (float4*)(ws + off);
  off += (size_t)B * CAP * 16;
  float4* sel_box = (float4*)(ws + off);
  off += (size_t)B * SEL * 16;
  float* sel_score = (float*)(ws + off);
  off += (size_t)B * SEL * 4;
  unsigned long long* mask = (unsigned long long*)(ws + off);
  off += (size_t)B * SEL * NW * 8;
  // total ~28 MB

  // Block geometry for per-batch streaming kernels: A = 261888 = 256*11*93.
  int chunks = (A % (256 * 11) == 0) ? 11 : 1;
  int bpb = (A + 256 * chunks - 1) / (256 * chunks);  // blocks per batch

  hipMemsetAsync(chist, 0, (size_t)B * 256 * 4 * 2, stream);  // chist+fhist
  k_decode<<<dim3(bpb, B), 256, 0, stream>>>((const float4*)anchors,
                                             (const float4*)deltas, scores,
                                             keys, chist, A, chunks);
  k_coarse<<<B, 256, 0, stream>>>(chist, cbArr, cumArr);
  k_fine<<<dim3(bpb, B), 256, 0, stream>>>(keys, cbArr, fhist, A, chunks);
  k_thresh<<<B, 256, 0, stream>>>(fhist, cbArr, cumArr, thresh, cnts);
  k_gather<<<dim3(bpb, B), 256, 0, stream>>>(keys, (const float4*)anchors,
                                             (const float4*)deltas, thresh,
                                             cnts, cand_sort, cand_box, A,
                                             chunks);
  k_sortsel<<<B, 512, 0, stream>>>(cnts, cand_sort, cand_box, sel_box,
                                   sel_score);
  k_nmsmask<<<dim3(NW, SEL / 64, B), 64, 0, stream>>>(sel_box, mask);
  k_scanout<<<B, 64, 0, stream>>>(sel_box, sel_score, mask, out);
}

// Round 6
// 344.416 us; speedup vs baseline: 4.9825x; 1.1622x over previous
//
#include <hip/hip_runtime.h>
#include <stdint.h>
#include <math.h>

// RPN proposal filtering: decode -> clip -> validity mask -> stable top-2000
// -> greedy NMS (IoU > 0.7) -> first 1000 kept -> (B, 1000, 5).
//
// R6: k_sortsel (108 us: 16-block bitonic, 78 LDS-bound barrier passes on 16
// CUs, occupancy 1.3%) replaced by enumeration sort: keys are strictly
// distinct u64s, so rank = count of greater keys gives the exact sorted slot.
// 256 blocks, no inter-thread deps, LDS broadcast tiles. Box payload is
// re-decoded from the anchor index embedded in the key, so cand_box and the
// bitonic payload array are gone; k_gather now writes only the 8B key.

#define IMGF 1024.0f
#define PRE_NMS 2000
#define POST_NMS 1000
#define NMS_THR 0.7f
#define MIN_SZ 16.0f
#define CAP 4096          // candidate buffer per batch
#define SEL 2048          // padded selection stride (>= PRE_NMS)
#define NW (SEL / 64)     // 32 mask words per row
#define CNT_STRIDE 32     // u32s per batch for counters (128 B -> own line)
#define KEY_NEGINF 0x007FFFFFu  // f2key(-inf)
#define MAXCHUNK 12

// Order-preserving float -> u32 key (all floats incl. -inf totally ordered).
__device__ __forceinline__ uint32_t f2key(float f) {
  uint32_t u = __float_as_uint(f);
  return (u & 0x80000000u) ? ~u : (u | 0x80000000u);
}
__device__ __forceinline__ float key2f(uint32_t k) {
  uint32_t u = (k & 0x80000000u) ? (k & 0x7FFFFFFFu) : ~k;
  return __uint_as_float(u);
}

__device__ __forceinline__ unsigned long long readlane_u64(unsigned long long v,
                                                           int lane) {
  unsigned int lo = __builtin_amdgcn_readlane((unsigned int)v, lane);
  unsigned int hi = __builtin_amdgcn_readlane((unsigned int)(v >> 32), lane);
  return ((unsigned long long)hi << 32) | lo;
}

// Mirrors reference _decode + clip, fp32.
__device__ __forceinline__ float4 decode_clip(float4 anc, float4 dlt) {
  float aw = anc.z - anc.x;
  float ah = anc.w - anc.y;
  float ax = anc.x + 0.5f * aw;
  float ay = anc.y + 0.5f * ah;
  float dw = fminf(dlt.z, 4.0f);
  float dh = fminf(dlt.w, 4.0f);
  float px = dlt.x * aw + ax;
  float py = dlt.y * ah + ay;
  float pw = expf(dw) * aw;
  float ph = expf(dh) * ah;
  float x1 = px - 0.5f * pw, y1 = py - 0.5f * ph;
  float x2 = px + 0.5f * pw, y2 = py + 0.5f * ph;
  x1 = fminf(fmaxf(x1, 0.0f), IMGF);
  y1 = fminf(fmaxf(y1, 0.0f), IMGF);
  x2 = fminf(fmaxf(x2, 0.0f), IMGF);
  y2 = fminf(fmaxf(y2, 0.0f), IMGF);
  return make_float4(x1, y1, x2, y2);
}

// K1: decode -> masked-score key; per-block LDS coarse hist of key>>24
// (finite keys only), ballot-match wave aggregation, one aggregated global
// flush per block. grid = (bpb, B).
__global__ void k_decode(const float4* __restrict__ anchors,
                         const float4* __restrict__ deltas,
                         const float* __restrict__ scores,
                         uint32_t* __restrict__ keys,
                         uint32_t* __restrict__ chist,
                         int A, int chunks) {
  int b = blockIdx.y;
  int t = threadIdx.x;  // 256
  int lane = t & 63;
  __shared__ uint32_t shist[256];
  shist[t] = 0;
  __syncthreads();
  int base_a = blockIdx.x * (chunks * 256);
  for (int c = 0; c < chunks; c++) {
    int a = base_a + c * 256 + t;
    bool inb = a < A;
    int ac = inb ? a : (A - 1);
    size_t i = (size_t)b * A + ac;
    float4 box = decode_clip(anchors[ac], deltas[i]);
    bool valid = (box.z - box.x >= MIN_SZ) && (box.w - box.y >= MIN_SZ);
    float ms = valid ? scores[i] : -INFINITY;
    uint32_t k = f2key(ms);
    if (inb) keys[i] = k;
    uint32_t bucket = k >> 24;
    bool fin = inb && (k != KEY_NEGINF);
    // lanes with equal bucket -> one LDS atomic by the leader
    unsigned long long match = __ballot(fin);
#pragma unroll
    for (int bit = 0; bit < 8; bit++) {
      bool hb = (bucket >> bit) & 1;
      unsigned long long bb = __ballot(hb && fin);
      match &= hb ? bb : ~bb;
    }
    if (fin && (__ffsll((long long)match) - 1 == lane))
      atomicAdd(&shist[bucket], (uint32_t)__popcll(match));
  }
  __syncthreads();
  uint32_t v = shist[t];
  if (v) atomicAdd(&chist[b * 256 + t], v);
}

// K2: pick coarse bucket cb s.t. countAbove(cb) < PRE_NMS <= countAbove(cb)+chist[cb].
__global__ void k_coarse(const uint32_t* __restrict__ chist,
                         int* __restrict__ cbArr,
                         uint32_t* __restrict__ cumArr) {
  int b = blockIdx.x;
  int t = threadIdx.x;  // 256
  __shared__ uint32_t sA[256];
  sA[t] = chist[b * 256 + t];
  for (int d = 1; d < 256; d <<= 1) {  // inclusive suffix scan
    __syncthreads();
    uint32_t v = sA[t] + ((t + d < 256) ? sA[t + d] : 0u);
    __syncthreads();
    sA[t] = v;
  }
  __syncthreads();
  if (t == 0 && sA[0] < PRE_NMS) {  // degenerate: < PRE_NMS finite entries
    cbArr[b] = -1;
    cumArr[b] = 0;
  }
  uint32_t nxt = (t < 255) ? sA[t + 1] : 0u;
  if (sA[t] >= PRE_NMS && nxt < PRE_NMS) {
    cbArr[b] = t;
    cumArr[b] = nxt;  // count strictly above coarse bucket t
  }
}

// K3: fine hist of key bits[23:16] for elements whose coarse bucket == cb[b].
__global__ void k_fine(const uint32_t* __restrict__ keys,
                       const int* __restrict__ cbArr,
                       uint32_t* __restrict__ fhist,
                       int A, int chunks) {
  int b = blockIdx.y;
  int t = threadIdx.x;  // 256
  int cb = cbArr[b];
  if (cb < 0) return;
  __shared__ uint32_t shist[256];
  shist[t] = 0;
  __syncthreads();
  int base_a = blockIdx.x * (chunks * 256);
  uint32_t cbu = (uint32_t)cb;
  for (int c = 0; c < chunks; c++) {
    int a = base_a + c * 256 + t;
    if (a >= A) break;
    uint32_t k = keys[(size_t)b * A + a];
    if ((k >> 24) == cbu && k != KEY_NEGINF)
      atomicAdd(&shist[(k >> 16) & 0xFFu], 1u);
  }
  __syncthreads();
  uint32_t v = shist[t];
  if (v) atomicAdd(&fhist[b * 256 + t], v);
}

// K4: final 16-bit threshold beta = (cb<<8)|d:
// count(key>>16 > beta) < PRE_NMS <= count(key>>16 >= beta), finite keys only.
__global__ void k_thresh(const uint32_t* __restrict__ fhist,
                         const int* __restrict__ cbArr,
                         const uint32_t* __restrict__ cumArr,
                         uint32_t* __restrict__ thresh,
                         uint32_t* __restrict__ cnts) {
  int b = blockIdx.x;
  int t = threadIdx.x;  // 256
  __shared__ uint32_t sA[256];
  if (t < 2) cnts[b * CNT_STRIDE + t] = 0;
  int cb = cbArr[b];
  if (cb < 0) {
    if (t == 0) thresh[b] = 0u;
    return;
  }
  uint32_t cumAbove = cumArr[b];
  sA[t] = fhist[b * 256 + t];
  for (int d = 1; d < 256; d <<= 1) {
    __syncthreads();
    uint32_t v = sA[t] + ((t + d < 256) ? sA[t + d] : 0u);
    __syncthreads();
    sA[t] = v;
  }
  __syncthreads();
  uint32_t nxt = (t < 255) ? sA[t + 1] : 0u;
  if (cumAbove + sA[t] >= PRE_NMS && cumAbove + nxt < PRE_NMS)
    thresh[b] = (uint32_t)((cb << 8) | t);
}

// K5: gather candidate KEYS ONLY (8B each), block-aggregated atomics: one
// atomicAdd per category per block. Strictly-above fills [0, c1); ties fill
// from CAP-1 downward; overflow ties dropped (only above 2096 ties/batch).
__global__ void k_gather(const uint32_t* __restrict__ keys,
                         const uint32_t* __restrict__ thresh,
                         uint32_t* __restrict__ cnts,
                         unsigned long long* __restrict__ cand_sort,
                         int A, int chunks) {
  int b = blockIdx.y;
  int t = threadIdx.x;  // 256
  int lane = t & 63;
  int w = t >> 6;  // wave 0..3
  __shared__ unsigned long long s_mA[MAXCHUNK * 4], s_mT[MAXCHUNK * 4];
  __shared__ uint32_t s_offA[MAXCHUNK * 4], s_offT[MAXCHUNK * 4];
  __shared__ uint32_t s_cA[MAXCHUNK * 4], s_cT[MAXCHUNK * 4];
  __shared__ uint32_t s_baseA, s_baseT;
  uint32_t beta = thresh[b];
  uint32_t kreg[MAXCHUNK];
  int base_a = blockIdx.x * (chunks * 256);
  for (int c = 0; c < chunks; c++) {
    int a = base_a + c * 256 + t;
    bool inb = a < A;
    uint32_t k = inb ? keys[(size_t)b * A + a] : KEY_NEGINF;
    kreg[c] = k;
    uint32_t bk = k >> 16;
    bool fin = (k != KEY_NEGINF);
    unsigned long long mA = __ballot(fin && (bk > beta));
    unsigned long long mT = __ballot(fin && (bk == beta));
    if (lane == 0) {
      s_mA[c * 4 + w] = mA;
      s_mT[c * 4 + w] = mT;
    }
  }
  __syncthreads();
  if (t < chunks * 4) {
    s_cA[t] = (uint32_t)__popcll(s_mA[t]);
    s_cT[t] = (uint32_t)__popcll(s_mT[t]);
  }
  __syncthreads();
  if (t == 0) {  // serial scan over <=44 entries, then ONE atomic per category
    uint32_t accA = 0, accT = 0;
    for (int id = 0; id < chunks * 4; id++) {
      s_offA[id] = accA;
      accA += s_cA[id];
      s_offT[id] = accT;
      accT += s_cT[id];
    }
    s_baseA = accA ? atomicAdd(&cnts[b * CNT_STRIDE + 0], accA) : 0u;
    s_baseT = accT ? atomicAdd(&cnts[b * CNT_STRIDE + 1], accT) : 0u;
  }
  __syncthreads();
  uint32_t baseA = s_baseA, baseT = s_baseT;
  unsigned long long lower = ((unsigned long long)1 << lane) - 1;
  for (int c = 0; c < chunks; c++) {
    int id = c * 4 + w;
    unsigned long long mA = s_mA[id], mT = s_mT[id];
    bool above = (mA >> lane) & 1;
    bool tie = (mT >> lane) & 1;
    if (!(above || tie)) continue;
    int pos;
    if (above) {
      pos = (int)(baseA + s_offA[id] + (uint32_t)__popcll(mA & lower));
      if (pos >= PRE_NMS) continue;  // defensive; cannot happen
    } else {
      pos = CAP - 1 - (int)(baseT + s_offT[id] + (uint32_t)__popcll(mT & lower));
      if (pos < PRE_NMS) continue;  // drop overflow ties
    }
    int a = base_a + c * 256 + t;
    // sort key: (score_key desc, anchor index asc) via descending u64 order
    cand_sort[(size_t)b * CAP + pos] =
        ((unsigned long long)kreg[c] << 32) | (uint32_t)(~(uint32_t)a);
  }
}

// K6a: default-fill selection (pads for degenerate batches; overwritten by
// k_rank for every live rank < SEL). grid = (SEL/256, B).
__global__ void k_fillsel(float4* __restrict__ sel_box,
                          float* __restrict__ sel_score) {
  int b = blockIdx.y;
  int r = blockIdx.x * 256 + threadIdx.x;
  sel_score[(size_t)b * SEL + r] = -INFINITY;
  sel_box[(size_t)b * SEL + r] = make_float4(0.0f, 0.0f, 0.0f, 0.0f);
}

// K6b: enumeration sort. Keys are strictly distinct ((score_key, ~anchor)),
// so rank = #{keys > mine} is the exact descending-sorted position. Each
// thread owns one slot, streams the batch's live slots through LDS broadcast
// tiles, and (if rank < SEL) decodes its box from the embedded anchor index.
// grid = (CAP/256, B). Fully parallel: 256 blocks, no cross-thread deps.
__global__ void k_rank(const unsigned long long* __restrict__ cand_sort,
                       const uint32_t* __restrict__ cnts,
                       const float4* __restrict__ anchors,
                       const float4* __restrict__ deltas,
                       float4* __restrict__ sel_box,
                       float* __restrict__ sel_score, int A) {
  int b = blockIdx.y;
  int t = threadIdx.x;  // 256
  uint32_t c1 = cnts[b * CNT_STRIDE + 0];
  if (c1 > PRE_NMS) c1 = PRE_NMS;
  uint32_t c2 = cnts[b * CNT_STRIDE + 1];
  if (c2 > CAP - PRE_NMS) c2 = CAP - PRE_NMS;
  int loTie = CAP - (int)c2;
  int bs = blockIdx.x * 256;
  if (bs >= (int)c1 && bs + 256 <= loTie) return;  // block fully in dead gap
  int s = bs + t;
  bool live = (s < (int)c1) || (s >= loTie);
  unsigned long long myKey = live ? cand_sort[(size_t)b * CAP + s] : 0ull;
  __shared__ unsigned long long tile[256];
  int rank = 0;
  for (int ts = 0; ts < CAP; ts += 256) {  // tile-skip is block-uniform
    if (ts >= (int)c1 && ts + 256 <= loTie) continue;
    int idx = ts + t;
    bool lv = (idx < (int)c1) || (idx >= loTie);
    __syncthreads();
    tile[t] = lv ? cand_sort[(size_t)b * CAP + idx] : 0ull;
    __syncthreads();
    if (live) {
#pragma unroll 8
      for (int j = 0; j < 256; j++) rank += (tile[j] > myKey) ? 1 : 0;
    }
  }
  if (live && rank < SEL) {
    uint32_t a = ~((uint32_t)myKey);
    float4 box = decode_clip(anchors[a], deltas[(size_t)b * A + a]);
    sel_score[(size_t)b * SEL + rank] = key2f((uint32_t)(myKey >> 32));
    sel_box[(size_t)b * SEL + rank] = box;
  }
}

// K7: suppression bitmask. mask[b][i][jb] bit jj set iff j = jb*64+jj > i,
// j < PRE_NMS, IoU(box_i, box_j) > NMS_THR. Rows in [PRE_NMS, SEL) zeroed
// so k_scanout never reads unwritten workspace.
__global__ void k_nmsmask(const float4* __restrict__ sel_box,
                          unsigned long long* __restrict__ mask) {
  int jb = blockIdx.x;  // col block
  int ib = blockIdx.y;  // row block
  int b = blockIdx.z;
  int t = threadIdx.x;  // 64
  int i = ib * 64 + t;
  if (jb < ib) {  // uniform per block; entire col tile is <= all rows
    mask[((size_t)b * SEL + i) * NW + jb] = 0ull;
    return;
  }
  __shared__ float4 cb[64];
  __shared__ float careb[64];
  int j0 = jb * 64;
  float4 cbx = sel_box[(size_t)b * SEL + j0 + t];
  cb[t] = cbx;
  careb[t] = (cbx.z - cbx.x) * (cbx.w - cbx.y);
  __syncthreads();
  if (i >= PRE_NMS) {  // pad rows: write zeros, never leave stale poison
    mask[((size_t)b * SEL + i) * NW + jb] = 0ull;
    return;
  }
  float4 a = sel_box[(size_t)b * SEL + i];
  float area_a = (a.z - a.x) * (a.w - a.y);
  unsigned long long bits = 0ull;
  int jmax = min(64, PRE_NMS - j0);
  for (int jj = 0; jj < jmax; jj++) {
    int j = j0 + jj;
    if (j <= i) continue;
    float4 bb = cb[jj];
    float ltx = fmaxf(a.x, bb.x), lty = fmaxf(a.y, bb.y);
    float rbx = fminf(a.z, bb.z), rby = fminf(a.w, bb.w);
    float w = fmaxf(rbx - ltx, 0.0f), hgt = fmaxf(rby - lty, 0.0f);
    float inter = w * hgt;
    float iou = inter / (area_a + careb[jj] - inter + 1e-6f);
    if (iou > NMS_THR) bits |= (1ull << jj);
  }
  mask[((size_t)b * SEL + i) * NW + jb] = bits;
}

// K8: one wave per batch. Serial greedy scan over EXACTLY PRE_NMS rows.
// removed word w in lane w's register; chunk word broadcast via v_readlane;
// rows prefetched 16-at-a-time into registers (double-buffered); wave-uniform
// scalar branches; early exit at POST_NMS.
__global__ void k_scanout(const float4* __restrict__ sel_box,
                          const float* __restrict__ sel_score,
                          const unsigned long long* __restrict__ mask,
                          float* __restrict__ out) {
  int b = blockIdx.x;
  int t = threadIdx.x;  // 64 = 1 wave
  int tw = t & 31;
  __shared__ uint32_t keptList[POST_NMS];
  unsigned long long removed = 0ull;  // lane w<32 owns word w
  int kc = 0;
  const unsigned long long* mbase = mask + (size_t)b * SEL * NW;
  for (int chunk = 0; chunk < SEL / 64; chunk++) {
    int rmax = PRE_NMS - chunk * 64;  // rows beyond PRE_NMS excluded
    if (rmax <= 0) break;
    if (rmax > 64) rmax = 64;
    uint32_t scb_all =
        __float_as_uint(sel_score[(size_t)b * SEL + chunk * 64 + t]);
    const unsigned long long* cbase = mbase + (size_t)chunk * 64 * NW;
    unsigned long long curw = readlane_u64(removed, chunk);
    unsigned long long m[16], mn[16];
#pragma unroll
    for (int j = 0; j < 16; j++) m[j] = cbase[j * NW + tw];
    for (int sub = 0; sub < 4; sub++) {
      if (sub < 3) {
#pragma unroll
        for (int j = 0; j < 16; j++)
          mn[j] = cbase[((sub + 1) * 16 + j) * NW + tw];
      }
#pragma unroll
      for (int j = 0; j < 16; j++) {
        int r = sub * 16 + j;
        if (r < rmax && !((curw >> r) & 1ull)) {
          removed |= m[j];
          curw = readlane_u64(removed, chunk);
          uint32_t scb = __builtin_amdgcn_readlane(scb_all, r);
          if (scb != 0xFF800000u) {  // score != -inf
            if (t == 0) keptList[kc] = (uint32_t)(chunk * 64 + r);
            kc++;
            if (kc == POST_NMS) goto writeout;
          }
        }
      }
      if (sub < 3) {
#pragma unroll
        for (int j = 0; j < 16; j++) m[j] = mn[j];
      }
    }
  }
writeout:
  __syncthreads();
  for (int r = t; r < POST_NMS; r += 64) {
    float4 bx = make_float4(0.0f, 0.0f, 0.0f, 0.0f);
    float sc = 0.0f;
    if (r < kc) {
      int i = (int)keptList[r];
      bx = sel_box[(size_t)b * SEL + i];
      sc = sel_score[(size_t)b * SEL + i];
    }
    float* o = out + ((size_t)b * POST_NMS + r) * 5;
    o[0] = bx.x;
    o[1] = bx.y;
    o[2] = bx.z;
    o[3] = bx.w;
    o[4] = sc;
  }
}

extern "C" void kernel_launch(void* const* d_in, const int* in_sizes, int n_in,
                              void* d_out, int out_size, void* d_ws, size_t ws_size,
                              hipStream_t stream) {
  const float* anchors = (const float*)d_in[0];  // (A, 4)
  const float* deltas = (const float*)d_in[1];   // (B, A, 4)
  const float* scores = (const float*)d_in[2];   // (B, A)
  int A = in_sizes[0] / 4;
  int BA = in_sizes[2];
  int B = BA / A;
  float* out = (float*)d_out;

  char* ws = (char*)d_ws;
  size_t off = 0;
  uint32_t* keys = (uint32_t*)(ws + off);
  off += (size_t)BA * 4;
  uint32_t* chist = (uint32_t*)(ws + off);
  off += (size_t)B * 256 * 4;
  uint32_t* fhist = (uint32_t*)(ws + off);
  off += (size_t)B * 256 * 4;
  int* cbArr = (int*)(ws + off);
  off += (size_t)B * 4;
  uint32_t* cumArr = (uint32_t*)(ws + off);
  off += (size_t)B * 4;
  uint32_t* thresh = (uint32_t*)(ws + off);
  off += (size_t)B * 4;
  off = (off + 127) & ~(size_t)127;
  uint32_t* cnts = (uint32_t*)(ws + off);
  off += (size_t)B * CNT_STRIDE * 4;
  off = (off + 15) & ~(size_t)15;
  unsigned long long* cand_sort = (unsigned long long*)(ws + off);
  off += (size_t)B * CAP * 8;
  float4* sel_box = (float4*)(ws + off);
  off += (size_t)B * SEL * 16;
  float* sel_score = (float*)(ws + off);
  off += (size_t)B * SEL * 4;
  unsigned long long* mask = (unsigned long long*)(ws + off);
  off += (size_t)B * SEL * NW * 8;
  // total ~27 MB

  // Block geometry for per-batch streaming kernels: A = 261888 = 256*11*93.
  int chunks = (A % (256 * 11) == 0) ? 11 : 1;
  int bpb = (A + 256 * chunks - 1) / (256 * chunks);  // blocks per batch

  hipMemsetAsync(chist, 0, (size_t)B * 256 * 4 * 2, stream);  // chist+fhist
  k_decode<<<dim3(bpb, B), 256, 0, stream>>>((const float4*)anchors,
                                             (const float4*)deltas, scores,
                                             keys, chist, A, chunks);
  k_coarse<<<B, 256, 0, stream>>>(chist, cbArr, cumArr);
  k_fine<<<dim3(bpb, B), 256, 0, stream>>>(keys, cbArr, fhist, A, chunks);
  k_thresh<<<B, 256, 0, stream>>>(fhist, cbArr, cumArr, thresh, cnts);
  k_gather<<<dim3(bpb, B), 256, 0, stream>>>(keys, thresh, cnts, cand_sort, A,
                                             chunks);
  k_fillsel<<<dim3(SEL / 256, B), 256, 0, stream>>>(sel_box, sel_score);
  k_rank<<<dim3(CAP / 256, B), 256, 0, stream>>>(cand_sort, cnts,
                                                 (const float4*)anchors,
                                                 (const float4*)deltas,
                                                 sel_box, sel_score, A);
  k_nmsmask<<<dim3(NW, SEL / 64, B), 64, 0, stream>>>(sel_box, mask);
  k_scanout<<<B, 64, 0, stream>>>(sel_box, sel_score, mask, out);
}